// Round 12
// baseline (276.452 us; speedup 1.0000x reference)
//
#include <hip/hip_runtime.h>
#include <math.h>

// Problem constants (fixed by setup_inputs)
#define BB 4
#define SS 512
#define EE 512
#define NH 8
#define HD 64
#define NC 128
#define NTAB 4096  // table intervals over sa in [-0.4, 0.4]

typedef _Float16 f16x8 __attribute__((ext_vector_type(8)));
typedef float f32x4 __attribute__((ext_vector_type(4)));

struct HL { _Float16 h, l; };

__device__ __forceinline__ float clampf(float v, float lo, float hi) {
  return fminf(fmaxf(v, lo), hi);
}
__device__ __forceinline__ HL split16(float x) {
  HL r;
  r.h = (_Float16)x;
  r.l = (_Float16)(x - (float)r.h);
  return r;
}

__device__ __forceinline__ float waveRedSum(float v) {
#pragma unroll
  for (int o = 32; o; o >>= 1) v += __shfl_xor(v, o);
  return v;
}
__device__ __forceinline__ float waveRedMax(float v) {
#pragma unroll
  for (int o = 32; o; o >>= 1) v = fmaxf(v, __shfl_xor(v, o));
  return v;
}

// ---------------------------------------------------------------------------
// K_prep: fused preprocessing:
//   blocks [0,17): sigmoid table
//   blocks [17,273): transpose+split the 4 weight matrices
//   block 273: zero the per-batch accumulators
__global__ __launch_bounds__(256) void k_prep(
    const float* __restrict__ w1, const float* __restrict__ b1,
    const float* __restrict__ w2, const float* __restrict__ b2,
    float* __restrict__ T,
    const float* __restrict__ Wq, const float* __restrict__ Wk,
    const float* __restrict__ Wv, const float* __restrict__ Wo,
    _Float16* __restrict__ Wth, _Float16* __restrict__ Wtl,
    float* __restrict__ acc) {
  const int bid = blockIdx.x;
  const int tid = threadIdx.x;
  if (bid < 17) {
    int idx = bid * 256 + tid;
    if (idx > NTAB) return;
    float sa = -0.4f + (float)idx * (0.8f / (float)NTAB);
    float ap = 0.f;
#pragma unroll 4
    for (int c = 0; c < NC; ++c) {
      float h = fminf(fmaxf(sa * w1[c] + b1[c], 0.f), 5.f);
      ap += h * w2[c];
    }
    ap = clampf(ap + b2[0], -5.f, 5.f);
    float tay = clampf(1.0f + 0.05f * (ap * 50.0f), 0.5f, 1.5f);
    T[idx] = 1.0f / (1.0f + expf(-tay));
  } else if (bid < 273) {
    const int j = bid - 17;           // [0,256)
    const int z = j >> 6;             // matrix
    const int rem = j & 63;
    const int k0 = (rem & 7) * 64, n0 = (rem >> 3) * 64;
    const float* W = (z == 0) ? Wq : (z == 1) ? Wk : (z == 2) ? Wv : Wo;
    __shared__ float Tt[64][68];
    const int r = tid >> 2, c = (tid & 3) * 16;
#pragma unroll
    for (int jj = 0; jj < 16; jj += 4)
      *(float4*)&Tt[r][c + jj] =
          *(const float4*)(W + (size_t)(k0 + r) * EE + n0 + c + jj);
    __syncthreads();
    f16x8 h0, l0, h1, l1;
#pragma unroll
    for (int jj = 0; jj < 8; ++jj) {
      HL r0 = split16(Tt[c + jj][r]);
      HL r1 = split16(Tt[c + 8 + jj][r]);
      h0[jj] = r0.h; l0[jj] = r0.l;
      h1[jj] = r1.h; l1[jj] = r1.l;
    }
    _Float16* dh = Wth + ((size_t)z * EE + n0 + r) * EE + k0 + c;
    _Float16* dl = Wtl + ((size_t)z * EE + n0 + r) * EE + k0 + c;
    *(f16x8*)dh = h0;
    *(f16x8*)(dh + 8) = h1;
    *(f16x8*)dl = l0;
    *(f16x8*)(dl + 8) = l1;
  } else {
    if (tid < 32) acc[tid] = 0.0f;
  }
}

// ---------------------------------------------------------------------------
// K_qkv: LDS-staged 3-term f16 MFMA GEMM with register-prefetch pipelining.
// A (=x) is read fp32 and SPLIT IN-REGISTER during staging (xh/xl buffers and
// the prep split phase are gone). Block = 64m x 64n, 4 waves stacked in m.
// q pre-scaled by 0.125. which==2 (V): transpose in LDS, store v_t.
__global__ __launch_bounds__(256) void k_qkv_mfma(
    const float* __restrict__ x,
    const _Float16* __restrict__ Wth, const _Float16* __restrict__ Wtl,
    const float* __restrict__ bq, const float* __restrict__ bk,
    const float* __restrict__ bv,
    _Float16* __restrict__ qh, _Float16* __restrict__ ql,
    _Float16* __restrict__ kh, _Float16* __restrict__ kl,
    _Float16* __restrict__ vth, _Float16* __restrict__ vtl) {
  const int which = blockIdx.z;
  const int tid = threadIdx.x;
  const int wave = tid >> 6, lane = tid & 63;
  const int quad = lane >> 4, l16 = lane & 15;
  const int m0 = blockIdx.y * 64;
  const int n0 = blockIdx.x * 64;
  const _Float16* Bh = Wth + (size_t)which * EE * EE;
  const _Float16* Bl = Wtl + (size_t)which * EE * EE;

  __shared__ __align__(16) char smpool[36864];
  _Float16(*LAh)[72] = (_Float16(*)[72])(smpool);
  _Float16(*LAl)[72] = (_Float16(*)[72])(smpool + 9216);
  _Float16(*LBh)[72] = (_Float16(*)[72])(smpool + 18432);
  _Float16(*LBl)[72] = (_Float16(*)[72])(smpool + 27648);
  float(*TR)[68] = (float(*)[68])(smpool);  // reused for V transpose

  const int sr0 = tid >> 3, sc0 = (tid & 7) * 8;
  const int sr1 = sr0 + 32;

  // prefetch stage k0=0: A fp32 (split later), B f16 hi/lo
  float4 rx0a = *(const float4*)(x + (size_t)(m0 + sr0) * EE + sc0);
  float4 rx0b = *(const float4*)(x + (size_t)(m0 + sr0) * EE + sc0 + 4);
  float4 rx1a = *(const float4*)(x + (size_t)(m0 + sr1) * EE + sc0);
  float4 rx1b = *(const float4*)(x + (size_t)(m0 + sr1) * EE + sc0 + 4);
  f16x8 rB0h = *(const f16x8*)(Bh + (size_t)(n0 + sr0) * EE + sc0);
  f16x8 rB0l = *(const f16x8*)(Bl + (size_t)(n0 + sr0) * EE + sc0);
  f16x8 rB1h = *(const f16x8*)(Bh + (size_t)(n0 + sr1) * EE + sc0);
  f16x8 rB1l = *(const f16x8*)(Bl + (size_t)(n0 + sr1) * EE + sc0);

  f32x4 acc[4] = {};
  for (int k0 = 0; k0 < EE; k0 += 64) {
    if (k0) __syncthreads();
    {
      float f0[8] = {rx0a.x, rx0a.y, rx0a.z, rx0a.w,
                     rx0b.x, rx0b.y, rx0b.z, rx0b.w};
      float f1[8] = {rx1a.x, rx1a.y, rx1a.z, rx1a.w,
                     rx1b.x, rx1b.y, rx1b.z, rx1b.w};
      f16x8 h0, l0, h1, l1;
#pragma unroll
      for (int j = 0; j < 8; ++j) {
        HL r0 = split16(f0[j]);
        HL r1 = split16(f1[j]);
        h0[j] = r0.h; l0[j] = r0.l;
        h1[j] = r1.h; l1[j] = r1.l;
      }
      *(f16x8*)&LAh[sr0][sc0] = h0;
      *(f16x8*)&LAl[sr0][sc0] = l0;
      *(f16x8*)&LAh[sr1][sc0] = h1;
      *(f16x8*)&LAl[sr1][sc0] = l1;
    }
    *(f16x8*)&LBh[sr0][sc0] = rB0h;
    *(f16x8*)&LBl[sr0][sc0] = rB0l;
    *(f16x8*)&LBh[sr1][sc0] = rB1h;
    *(f16x8*)&LBl[sr1][sc0] = rB1l;
    __syncthreads();
    if (k0 + 64 < EE) {
      const int kn = k0 + 64;
      rx0a = *(const float4*)(x + (size_t)(m0 + sr0) * EE + kn + sc0);
      rx0b = *(const float4*)(x + (size_t)(m0 + sr0) * EE + kn + sc0 + 4);
      rx1a = *(const float4*)(x + (size_t)(m0 + sr1) * EE + kn + sc0);
      rx1b = *(const float4*)(x + (size_t)(m0 + sr1) * EE + kn + sc0 + 4);
      rB0h = *(const f16x8*)(Bh + (size_t)(n0 + sr0) * EE + kn + sc0);
      rB0l = *(const f16x8*)(Bl + (size_t)(n0 + sr0) * EE + kn + sc0);
      rB1h = *(const f16x8*)(Bh + (size_t)(n0 + sr1) * EE + kn + sc0);
      rB1l = *(const f16x8*)(Bl + (size_t)(n0 + sr1) * EE + kn + sc0);
    }
#pragma unroll
    for (int kk = 0; kk < 64; kk += 32) {
      f16x8 ah = *(const f16x8*)&LAh[wave * 16 + l16][kk + quad * 8];
      f16x8 al = *(const f16x8*)&LAl[wave * 16 + l16][kk + quad * 8];
#pragma unroll
      for (int nt = 0; nt < 4; ++nt) {
        f16x8 bhf = *(const f16x8*)&LBh[nt * 16 + l16][kk + quad * 8];
        f16x8 blf = *(const f16x8*)&LBl[nt * 16 + l16][kk + quad * 8];
        acc[nt] = __builtin_amdgcn_mfma_f32_16x16x32_f16(ah, bhf, acc[nt], 0, 0, 0);
        acc[nt] = __builtin_amdgcn_mfma_f32_16x16x32_f16(ah, blf, acc[nt], 0, 0, 0);
        acc[nt] = __builtin_amdgcn_mfma_f32_16x16x32_f16(al, bhf, acc[nt], 0, 0, 0);
      }
    }
  }
  const float* bias = (which == 0) ? bq : (which == 1) ? bk : bv;
  if (which == 2) {
    // V path: bias-add, transpose via LDS, store split-f16 [bh][d][si]
    __syncthreads();  // main-loop LDS reads done before overwrite
#pragma unroll
    for (int nt = 0; nt < 4; ++nt) {
      const int dcol = nt * 16 + l16;             // d within head
      const float bb = bias[n0 + nt * 16 + l16];  // n0 = head*64
#pragma unroll
      for (int r = 0; r < 4; ++r)
        TR[dcol][wave * 16 + quad * 4 + r] = acc[nt][r] + bb;
    }
    __syncthreads();
    const int d = tid >> 2, cc = (tid & 3) * 16;
    const int bh = (m0 >> 9) * NH + (n0 >> 6);
    const int si0 = m0 & 511;
    f16x8 h0, l0, h1, l1;
#pragma unroll
    for (int jj = 0; jj < 8; ++jj) {
      HL r0 = split16(TR[d][cc + jj]);
      HL r1 = split16(TR[d][cc + 8 + jj]);
      h0[jj] = r0.h; l0[jj] = r0.l;
      h1[jj] = r1.h; l1[jj] = r1.l;
    }
    _Float16* dh = vth + ((size_t)bh * HD + d) * SS + si0 + cc;
    _Float16* dl = vtl + ((size_t)bh * HD + d) * SS + si0 + cc;
    *(f16x8*)dh = h0;
    *(f16x8*)(dh + 8) = h1;
    *(f16x8*)dl = l0;
    *(f16x8*)(dl + 8) = l1;
  } else {
    const float postscale = (which == 0) ? 0.125f : 1.0f;
    const int mbase = m0 + wave * 16 + quad * 4;
#pragma unroll
    for (int nt = 0; nt < 4; ++nt) {
      const int col = n0 + nt * 16 + l16;
      const float bb = bias[col];
      const int hh = col >> 6, d = col & 63;
#pragma unroll
      for (int r = 0; r < 4; ++r) {
        const int mm = mbase + r;
        const int b_ = mm >> 9, si = mm & 511;
        const size_t idx = (((size_t)(b_ * NH + hh)) * SS + si) * HD + d;
        const float val = (acc[nt][r] + bb) * postscale;
        HL sp = split16(val);
        (which ? kh : qh)[idx] = sp.h;
        (which ? kl : ql)[idx] = sp.l;
      }
    }
  }
}

// ---------------------------------------------------------------------------
// K_scores: s = clip(q.k^T, -15, 15) via 3-term f16 MFMA (q pre-scaled).
// LDS-staged. grid (8 jT, 8 iT, 32 bh), block 256 (4 waves stacked in m).
__global__ __launch_bounds__(256) void k_scores_mfma(
    const _Float16* __restrict__ qh, const _Float16* __restrict__ ql,
    const _Float16* __restrict__ kh, const _Float16* __restrict__ kl,
    float* __restrict__ s) {
  const int bh = blockIdx.z;
  const int i0 = blockIdx.y * 64, j0 = blockIdx.x * 64;
  const int tid = threadIdx.x;
  const int wave = tid >> 6, lane = tid & 63;
  const int quad = lane >> 4, l16 = lane & 15;

  __shared__ _Float16 Qh[64][72], Ql[64][72], Kh[64][72], Kl[64][72];
  const int r = tid >> 2, c = (tid & 3) * 16;
  {
    const size_t qoff = ((size_t)bh * SS + i0 + r) * HD + c;
    const size_t koff = ((size_t)bh * SS + j0 + r) * HD + c;
    *(f16x8*)&Qh[r][c] = *(const f16x8*)(qh + qoff);
    *(f16x8*)&Qh[r][c + 8] = *(const f16x8*)(qh + qoff + 8);
    *(f16x8*)&Ql[r][c] = *(const f16x8*)(ql + qoff);
    *(f16x8*)&Ql[r][c + 8] = *(const f16x8*)(ql + qoff + 8);
    *(f16x8*)&Kh[r][c] = *(const f16x8*)(kh + koff);
    *(f16x8*)&Kh[r][c + 8] = *(const f16x8*)(kh + koff + 8);
    *(f16x8*)&Kl[r][c] = *(const f16x8*)(kl + koff);
    *(f16x8*)&Kl[r][c + 8] = *(const f16x8*)(kl + koff + 8);
  }
  __syncthreads();

  f16x8 a_hi[2], a_lo[2];
#pragma unroll
  for (int ks = 0; ks < 2; ++ks) {
    a_hi[ks] = *(const f16x8*)&Qh[wave * 16 + l16][ks * 32 + quad * 8];
    a_lo[ks] = *(const f16x8*)&Ql[wave * 16 + l16][ks * 32 + quad * 8];
  }
  f32x4 acc[4] = {};
#pragma unroll
  for (int ks = 0; ks < 2; ++ks) {
#pragma unroll
    for (int t = 0; t < 4; ++t) {
      f16x8 b_hi = *(const f16x8*)&Kh[t * 16 + l16][ks * 32 + quad * 8];
      f16x8 b_lo = *(const f16x8*)&Kl[t * 16 + l16][ks * 32 + quad * 8];
      acc[t] = __builtin_amdgcn_mfma_f32_16x16x32_f16(a_hi[ks], b_hi,
                                                      acc[t], 0, 0, 0);
      acc[t] = __builtin_amdgcn_mfma_f32_16x16x32_f16(a_hi[ks], b_lo,
                                                      acc[t], 0, 0, 0);
      acc[t] = __builtin_amdgcn_mfma_f32_16x16x32_f16(a_lo[ks], b_hi,
                                                      acc[t], 0, 0, 0);
    }
  }
  float* sb = s + (size_t)bh * SS * SS;
#pragma unroll
  for (int t = 0; t < 4; ++t) {
#pragma unroll
    for (int r2 = 0; r2 < 4; ++r2) {
      float val = clampf(acc[t][r2], -15.0f, 15.0f);  // inputs finite
      sb[(size_t)(i0 + wave * 16 + quad * 4 + r2) * SS + j0 + t * 16 + l16] = val;
    }
  }
}

// ---------------------------------------------------------------------------
// K_rowstat: per-row fused ma + autopoietic transform. 512 blocks x 256
// threads, wave w handles row blockIdx*4+w. Per-batch stats go directly to
// device-scope atomics in acc[b][8] (k_consts is gone; av recomputes c0-c2).
__global__ __launch_bounds__(256) void k_rowstat(
    const float* __restrict__ s, const float* __restrict__ T,
    float* __restrict__ ma, float* __restrict__ t_un,
    float* __restrict__ acc) {
  const int row = blockIdx.x * 4 + (threadIdx.x >> 6);  // b*S + i
  const int b_ = row >> 9, i = row & 511;
  const int lane = threadIdx.x & 63;

  float4 a0 = {0.f, 0.f, 0.f, 0.f}, a1 = {0.f, 0.f, 0.f, 0.f};
#pragma unroll
  for (int hh = 0; hh < NH; ++hh) {
    const float4* p = reinterpret_cast<const float4*>(
                          s + (((size_t)(b_ * NH + hh) * SS) + i) * SS) +
                      lane * 2;
    float4 u0 = p[0], u1 = p[1];
    a0.x += u0.x; a0.y += u0.y; a0.z += u0.z; a0.w += u0.w;
    a1.x += u1.x; a1.y += u1.y; a1.z += u1.z; a1.w += u1.w;
  }
  float m[8] = {a0.x * 0.125f, a0.y * 0.125f, a0.z * 0.125f, a0.w * 0.125f,
                a1.x * 0.125f, a1.y * 0.125f, a1.z * 0.125f, a1.w * 0.125f};
  {
    float4* mp = reinterpret_cast<float4*>(ma + ((size_t)b_ * SS + i) * SS) +
                 lane * 2;
    float4 w0 = {m[0], m[1], m[2], m[3]}, w1v = {m[4], m[5], m[6], m[7]};
    mp[0] = w0;
    mp[1] = w1v;
  }
  float sma = 0.f, sma2 = 0.f, mabs = 0.f;
#pragma unroll
  for (int e = 0; e < 8; ++e) {
    sma += m[e];
    sma2 += m[e] * m[e];
    mabs = fmaxf(mabs, fabsf(m[e]));
  }
  sma = waveRedSum(sma);
  sma2 = waveRedSum(sma2);
  mabs = waveRedMax(mabs);

  float ex[8], esum = 0.f;
#pragma unroll
  for (int e = 0; e < 8; ++e) {
    ex[e] = expf(clampf(m[e], -10.f, 10.f));
    esum += ex[e];
  }
  esum = waveRedSum(esum);
  float inv = 1.0f / esum;
  float Hv[8], sH = 0.f;
#pragma unroll
  for (int e = 0; e < 8; ++e) {
    float p = ex[e] * inv;
    Hv[e] = -p * logf(p + 1e-6f);
    sH += Hv[e];
  }
  sH = waveRedSum(sH);

  float fx[8], fsum = 0.f;
#pragma unroll
  for (int e = 0; e < 8; ++e) {
    fx[e] = expf(3.0f * Hv[e]);
    fsum += fx[e];
  }
  fsum = waveRedSum(fsum);
  float finv = 1.0f / fsum;

  float t[8], st = 0.f, st2 = 0.f;
#pragma unroll
  for (int e = 0; e < 8; ++e) {
    float sa = clampf(m[e], -8.f, 8.f) * 0.05f;
    float pos = (sa + 0.4f) * ((float)NTAB / 0.8f);
    int idx = (int)pos;
    idx = idx < 0 ? 0 : (idx > NTAB - 1 ? NTAB - 1 : idx);
    float frac = pos - (float)idx;
    float g0 = T[idx], g1 = T[idx + 1];
    float sig = g0 + (g1 - g0) * frac;
    t[e] = sig * fx[e] * finv;
    st += t[e];
    st2 += t[e] * t[e];
  }
  st = waveRedSum(st);
  st2 = waveRedSum(st2);
  {
    float4* tp = reinterpret_cast<float4*>(t_un + ((size_t)b_ * SS + i) * SS) +
                 lane * 2;
    float4 w0 = {t[0], t[1], t[2], t[3]}, w1v = {t[4], t[5], t[6], t[7]};
    tp[0] = w0;
    tp[1] = w1v;
  }
  if (lane == 0) {
    float* ap = acc + b_ * 8;
    atomicAdd(&ap[0], sma);
    atomicAdd(&ap[1], sma2);
    atomicMax((unsigned int*)&ap[2], __float_as_uint(mabs));
    atomicAdd(&ap[3], st);
    atomicAdd(&ap[4], st2);
    atomicAdd(&ap[5], sH);
  }
}

// ---------------------------------------------------------------------------
// K_av_fused: out = softmax(blend(s)) @ v with NO materialized p; c0/c1/c2
// recomputed per block from the atomically-accumulated batch stats.
// m-tile = 32 rows -> grid (16 mb, 32 bh). Stage threads (tid<128) compute
// unnormalized e' = exp(blend)*2^-16, split into LDS, accumulate Z partials.
__global__ __launch_bounds__(256) void k_av_fused(
    const float* __restrict__ s, const float* __restrict__ ma,
    const float* __restrict__ t_un, const float* __restrict__ acc_g,
    const float* __restrict__ tau, const _Float16* __restrict__ vth,
    const _Float16* __restrict__ vtl, _Float16* __restrict__ oh,
    _Float16* __restrict__ ol) {
  const int bh = blockIdx.y;
  const int b_ = bh >> 3, hh = bh & 7;
  const int m0 = blockIdx.x * 32;
  const int tid = threadIdx.x;
  const int wave = tid >> 6, lane = tid & 63;
  const int quad = lane >> 4, l16 = lane & 15;

  // per-batch blend constants (formerly k_consts) -- ~30 flops, redundant
  float c0, c1, c2;
  {
    const float* ap = acc_g + b_ * 8;
    const float N = (float)(SS * SS);
    float sma = ap[0], sma2 = ap[1];
    float mabs = __uint_as_float(((const unsigned int*)ap)[2]);
    float st = ap[3], st2 = ap[4], sH = ap[5];
    float eo = sqrtf(sma2) + 1e-4f;
    float et = sqrtf(st2) + 1e-4f;
    float r = clampf(eo / et, 0.8f, 1.2f);
    float tmean = r * st / N;
    float om = sma / N;
    float vart = r * r * fmaxf(st2 / N - (st / N) * (st / N), 0.f);
    float tstd = sqrtf(fmaxf(vart, 0.01f));
    float varo = fmaxf(sma2 / N - om * om, 0.f);
    float ostd = sqrtf(fmaxf(varo, 0.01f));
    float gd = clampf(ostd / tstd, 0.8f, 1.2f);
    float ar = clampf(mabs, 1.f, 10.f);
    float sm = clampf(0.3f / log1pf(ar), 0.1f, 0.5f);
    float ent = sH / N;
    float ne = ent / logf((float)SS);
    float rr = 0.4f * (1.f - clampf(ne, 0.f, 0.4f));
    float G = sm * gd;
    c0 = rr * (1.f - G) * tmean;
    c1 = rr * G * r;
    c2 = rr;
  }
  const float itau = 1.0f / tau[0];

  __shared__ _Float16 Ph[32][40], Pl[32][40];
  __shared__ float Zp[32][4];

  const bool stager = (tid < 128);
  const int srow = tid >> 2;          // 0..31 valid when stager
  const int ci = tid & 3;
  const int schunk = ci * 8;
  const size_t sbase = ((size_t)bh * SS + m0 + (srow & 31)) * SS + schunk;
  const size_t mbase = ((size_t)b_ * SS + m0 + (srow & 31)) * SS + schunk;

  float4 sv0, sv1, mv0, mv1, tv0, tv1;
  if (stager) {
    sv0 = *(const float4*)(s + sbase);
    sv1 = *(const float4*)(s + sbase + 4);
    mv0 = *(const float4*)(ma + mbase);
    mv1 = *(const float4*)(ma + mbase + 4);
    tv0 = *(const float4*)(t_un + mbase);
    tv1 = *(const float4*)(t_un + mbase + 4);
  }

  float zpart = 0.f;
  f32x4 acc[2] = {};
  for (int k0 = 0; k0 < SS; k0 += 32) {
    if (k0) __syncthreads();  // prior-stage LDS reads done
    if (stager) {
      float svv[8] = {sv0.x, sv0.y, sv0.z, sv0.w, sv1.x, sv1.y, sv1.z, sv1.w};
      float mvv[8] = {mv0.x, mv0.y, mv0.z, mv0.w, mv1.x, mv1.y, mv1.z, mv1.w};
      float tvv[8] = {tv0.x, tv0.y, tv0.z, tv0.w, tv1.x, tv1.y, tv1.z, tv1.w};
      f16x8 hv, lv;
#pragma unroll
      for (int j = 0; j < 8; ++j) {
        float vv = (svv[j] + c0 + c1 * tvv[j] - c2 * mvv[j]) * itau;
        float e = expf(vv) * 1.52587890625e-05f;  // * 2^-16
        zpart += e;
        HL r = split16(e);
        hv[j] = r.h;
        lv[j] = r.l;
      }
      *(f16x8*)&Ph[srow][schunk] = hv;
      *(f16x8*)&Pl[srow][schunk] = lv;
    }
    __syncthreads();
    if (stager && k0 + 32 < SS) {
      sv0 = *(const float4*)(s + sbase + k0 + 32);
      sv1 = *(const float4*)(s + sbase + k0 + 36);
      mv0 = *(const float4*)(ma + mbase + k0 + 32);
      mv1 = *(const float4*)(ma + mbase + k0 + 36);
      tv0 = *(const float4*)(t_un + mbase + k0 + 32);
      tv1 = *(const float4*)(t_un + mbase + k0 + 36);
    }
    const size_t boff = ((size_t)bh * HD + wave * 16 + l16) * SS + k0 + quad * 8;
    f16x8 bh_ = *(const f16x8*)(vth + boff);
    f16x8 bl_ = *(const f16x8*)(vtl + boff);
#pragma unroll
    for (int mt = 0; mt < 2; ++mt) {
      f16x8 ah = *(const f16x8*)&Ph[mt * 16 + l16][quad * 8];
      f16x8 al = *(const f16x8*)&Pl[mt * 16 + l16][quad * 8];
      acc[mt] = __builtin_amdgcn_mfma_f32_16x16x32_f16(ah, bh_, acc[mt], 0, 0, 0);
      acc[mt] = __builtin_amdgcn_mfma_f32_16x16x32_f16(ah, bl_, acc[mt], 0, 0, 0);
      acc[mt] = __builtin_amdgcn_mfma_f32_16x16x32_f16(al, bh_, acc[mt], 0, 0, 0);
    }
  }
  __syncthreads();
  if (stager) Zp[srow][ci] = zpart;
  __syncthreads();
#pragma unroll
  for (int mt = 0; mt < 2; ++mt) {
#pragma unroll
    for (int r = 0; r < 4; ++r) {
      const int lr = mt * 16 + quad * 4 + r;  // local row 0..31
      const float Z = Zp[lr][0] + Zp[lr][1] + Zp[lr][2] + Zp[lr][3];
      const float oV = acc[mt][r] / Z;
      const int si = m0 + lr;
      const size_t idx =
          ((size_t)(b_ * SS + si)) * EE + hh * HD + wave * 16 + l16;
      HL sp = split16(oV);
      oh[idx] = sp.h;
      ol[idx] = sp.l;
    }
  }
}

// ---------------------------------------------------------------------------
// K_out: LDS-staged 3-term f16 MFMA GEMM with register-prefetch pipelining,
// fp32 output + bias. grid (8 nb, 32 mb), block 256.
__global__ __launch_bounds__(256) void k_out_mfma(
    const _Float16* __restrict__ oh, const _Float16* __restrict__ ol,
    const _Float16* __restrict__ Wth, const _Float16* __restrict__ Wtl,
    const float* __restrict__ bo, float* __restrict__ out) {
  const int tid = threadIdx.x;
  const int wave = tid >> 6, lane = tid & 63;
  const int quad = lane >> 4, l16 = lane & 15;
  const int m0 = blockIdx.y * 64;
  const int n0 = blockIdx.x * 64;
  const _Float16* Bh = Wth + (size_t)3 * EE * EE;  // Wo^T
  const _Float16* Bl = Wtl + (size_t)3 * EE * EE;

  __shared__ _Float16 LAh[64][72], LAl[64][72], LBh[64][72], LBl[64][72];

  const int sr0 = tid >> 3, sc0 = (tid & 7) * 8;
  const int sr1 = sr0 + 32;

  f16x8 rA0h = *(const f16x8*)(oh + (size_t)(m0 + sr0) * EE + sc0);
  f16x8 rA0l = *(const f16x8*)(ol + (size_t)(m0 + sr0) * EE + sc0);
  f16x8 rB0h = *(const f16x8*)(Bh + (size_t)(n0 + sr0) * EE + sc0);
  f16x8 rB0l = *(const f16x8*)(Bl + (size_t)(n0 + sr0) * EE + sc0);
  f16x8 rA1h = *(const f16x8*)(oh + (size_t)(m0 + sr1) * EE + sc0);
  f16x8 rA1l = *(const f16x8*)(ol + (size_t)(m0 + sr1) * EE + sc0);
  f16x8 rB1h = *(const f16x8*)(Bh + (size_t)(n0 + sr1) * EE + sc0);
  f16x8 rB1l = *(const f16x8*)(Bl + (size_t)(n0 + sr1) * EE + sc0);

  f32x4 acc[4] = {};
  for (int k0 = 0; k0 < EE; k0 += 64) {
    if (k0) __syncthreads();
    *(f16x8*)&LAh[sr0][sc0] = rA0h;
    *(f16x8*)&LAl[sr0][sc0] = rA0l;
    *(f16x8*)&LBh[sr0][sc0] = rB0h;
    *(f16x8*)&LBl[sr0][sc0] = rB0l;
    *(f16x8*)&LAh[sr1][sc0] = rA1h;
    *(f16x8*)&LAl[sr1][sc0] = rA1l;
    *(f16x8*)&LBh[sr1][sc0] = rB1h;
    *(f16x8*)&LBl[sr1][sc0] = rB1l;
    __syncthreads();
    if (k0 + 64 < EE) {
      const int kn = k0 + 64;
      rA0h = *(const f16x8*)(oh + (size_t)(m0 + sr0) * EE + kn + sc0);
      rA0l = *(const f16x8*)(ol + (size_t)(m0 + sr0) * EE + kn + sc0);
      rB0h = *(const f16x8*)(Bh + (size_t)(n0 + sr0) * EE + kn + sc0);
      rB0l = *(const f16x8*)(Bl + (size_t)(n0 + sr0) * EE + kn + sc0);
      rA1h = *(const f16x8*)(oh + (size_t)(m0 + sr1) * EE + kn + sc0);
      rA1l = *(const f16x8*)(ol + (size_t)(m0 + sr1) * EE + kn + sc0);
      rB1h = *(const f16x8*)(Bh + (size_t)(n0 + sr1) * EE + kn + sc0);
      rB1l = *(const f16x8*)(Bl + (size_t)(n0 + sr1) * EE + kn + sc0);
    }
#pragma unroll
    for (int kk = 0; kk < 64; kk += 32) {
      f16x8 ah = *(const f16x8*)&LAh[wave * 16 + l16][kk + quad * 8];
      f16x8 al = *(const f16x8*)&LAl[wave * 16 + l16][kk + quad * 8];
#pragma unroll
      for (int nt = 0; nt < 4; ++nt) {
        f16x8 bhf = *(const f16x8*)&LBh[nt * 16 + l16][kk + quad * 8];
        f16x8 blf = *(const f16x8*)&LBl[nt * 16 + l16][kk + quad * 8];
        acc[nt] = __builtin_amdgcn_mfma_f32_16x16x32_f16(ah, bhf, acc[nt], 0, 0, 0);
        acc[nt] = __builtin_amdgcn_mfma_f32_16x16x32_f16(ah, blf, acc[nt], 0, 0, 0);
        acc[nt] = __builtin_amdgcn_mfma_f32_16x16x32_f16(al, bhf, acc[nt], 0, 0, 0);
      }
    }
  }
  const int mbase = m0 + wave * 16 + quad * 4;
#pragma unroll
  for (int nt = 0; nt < 4; ++nt) {
    const int col = n0 + nt * 16 + l16;
    const float bb = bo[col];
#pragma unroll
    for (int r = 0; r < 4; ++r) {
      const int m = mbase + r;
      out[(size_t)m * EE + col] = acc[nt][r] + bb;
    }
  }
}

// ---------------------------------------------------------------------------
extern "C" void kernel_launch(void* const* d_in, const int* in_sizes, int n_in,
                              void* d_out, int out_size, void* d_ws,
                              size_t ws_size, hipStream_t stream) {
  const float* x = (const float*)d_in[0];
  const float* Wq = (const float*)d_in[1];
  const float* bq = (const float*)d_in[2];
  const float* Wk = (const float*)d_in[3];
  const float* bk = (const float*)d_in[4];
  const float* Wv = (const float*)d_in[5];
  const float* bv = (const float*)d_in[6];
  const float* Wo = (const float*)d_in[7];
  const float* bo = (const float*)d_in[8];
  const float* w1 = (const float*)d_in[9];
  const float* b1 = (const float*)d_in[10];
  const float* w2 = (const float*)d_in[11];
  const float* b2 = (const float*)d_in[12];
  const float* tau = (const float*)d_in[13];
  float* out = (float*)d_out;

  const size_t NX = (size_t)2048 * EE;           // 1M elems (o)
  const size_t NW = (size_t)4 * EE * EE;         // 1M elems (4 W's)
  const size_t NQK = (size_t)BB * NH * SS * HD;  // 1M elems
  const size_t NS = (size_t)BB * NH * SS * SS;   // 8.39M elems

  _Float16* Wth = (_Float16*)d_ws;
  _Float16* Wtl = Wth + NW;
  _Float16* qh = Wtl + NW;
  _Float16* ql = qh + NQK;
  _Float16* kh = ql + NQK;
  _Float16* kl = kh + NQK;
  _Float16* vth = kl + NQK;
  _Float16* vtl = vth + NQK;
  _Float16* oh = vtl + NQK;
  _Float16* ol = oh + NX;
  float* s = (float*)(ol + NX);
  float* ma = s + NS;
  float* t_un = ma + (size_t)BB * SS * SS;
  float* T = t_un + (size_t)BB * SS * SS;
  float* acc = T + 8192;   // 32 floats (per-batch stats)

  k_prep<<<274, 256, 0, stream>>>(w1, b1, w2, b2, T, Wq, Wk, Wv, Wo, Wth, Wtl,
                                  acc);
  k_qkv_mfma<<<dim3(8, 32, 3), 256, 0, stream>>>(x, Wth, Wtl, bq, bk, bv, qh,
                                                 ql, kh, kl, vth, vtl);
  k_scores_mfma<<<dim3(8, 8, 32), 256, 0, stream>>>(qh, ql, kh, kl, s);
  k_rowstat<<<512, 256, 0, stream>>>(s, T, ma, t_un, acc);
  k_av_fused<<<dim3(16, 32), 256, 0, stream>>>(s, ma, t_un, acc, tau, vth, vtl,
                                               oh, ol);
  k_out_mfma<<<dim3(8, 32), 256, 0, stream>>>(oh, ol, Wth, Wtl, bo, out);
}

// Round 13
// 164.743 us; speedup vs baseline: 1.6781x; 1.6781x over previous
//
#include <hip/hip_runtime.h>
#include <math.h>

// Problem constants (fixed by setup_inputs)
#define BB 4
#define SS 512
#define EE 512
#define NH 8
#define HD 64
#define NC 128
#define NTAB 4096  // table intervals over sa in [-0.4, 0.4]

typedef _Float16 f16x8 __attribute__((ext_vector_type(8)));
typedef float f32x4 __attribute__((ext_vector_type(4)));

struct HL { _Float16 h, l; };

__device__ __forceinline__ float clampf(float v, float lo, float hi) {
  return fminf(fmaxf(v, lo), hi);
}
__device__ __forceinline__ HL split16(float x) {
  HL r;
  r.h = (_Float16)x;
  r.l = (_Float16)(x - (float)r.h);
  return r;
}

__device__ __forceinline__ float waveRedSum(float v) {
#pragma unroll
  for (int o = 32; o; o >>= 1) v += __shfl_xor(v, o);
  return v;
}
__device__ __forceinline__ float waveRedMax(float v) {
#pragma unroll
  for (int o = 32; o; o >>= 1) v = fmaxf(v, __shfl_xor(v, o));
  return v;
}
// blockDim.x == 256 (4 waves) assumed
__device__ __forceinline__ float blockRedSum(float v, float* red) {
  int tid = threadIdx.x;
  v = waveRedSum(v);
  __syncthreads();
  if ((tid & 63) == 0) red[tid >> 6] = v;
  __syncthreads();
  return red[0] + red[1] + red[2] + red[3];
}
__device__ __forceinline__ float blockRedMax(float v, float* red) {
  int tid = threadIdx.x;
  v = waveRedMax(v);
  __syncthreads();
  if ((tid & 63) == 0) red[tid >> 6] = v;
  __syncthreads();
  return fmaxf(fmaxf(red[0], red[1]), fmaxf(red[2], red[3]));
}

// ---------------------------------------------------------------------------
// K_prep: fused preprocessing:
//   blocks [0,17): sigmoid table
//   blocks [17,273): transpose+split the 4 weight matrices
__global__ __launch_bounds__(256) void k_prep(
    const float* __restrict__ w1, const float* __restrict__ b1,
    const float* __restrict__ w2, const float* __restrict__ b2,
    float* __restrict__ T,
    const float* __restrict__ Wq, const float* __restrict__ Wk,
    const float* __restrict__ Wv, const float* __restrict__ Wo,
    _Float16* __restrict__ Wth, _Float16* __restrict__ Wtl) {
  const int bid = blockIdx.x;
  const int tid = threadIdx.x;
  if (bid < 17) {
    int idx = bid * 256 + tid;
    if (idx > NTAB) return;
    float sa = -0.4f + (float)idx * (0.8f / (float)NTAB);
    float ap = 0.f;
#pragma unroll 4
    for (int c = 0; c < NC; ++c) {
      float h = fminf(fmaxf(sa * w1[c] + b1[c], 0.f), 5.f);
      ap += h * w2[c];
    }
    ap = clampf(ap + b2[0], -5.f, 5.f);
    float tay = clampf(1.0f + 0.05f * (ap * 50.0f), 0.5f, 1.5f);
    T[idx] = 1.0f / (1.0f + expf(-tay));
  } else {
    const int j = bid - 17;           // [0,256)
    const int z = j >> 6;             // matrix
    const int rem = j & 63;
    const int k0 = (rem & 7) * 64, n0 = (rem >> 3) * 64;
    const float* W = (z == 0) ? Wq : (z == 1) ? Wk : (z == 2) ? Wv : Wo;
    __shared__ float Tt[64][68];
    const int r = tid >> 2, c = (tid & 3) * 16;
#pragma unroll
    for (int jj = 0; jj < 16; jj += 4)
      *(float4*)&Tt[r][c + jj] =
          *(const float4*)(W + (size_t)(k0 + r) * EE + n0 + c + jj);
    __syncthreads();
    f16x8 h0, l0, h1, l1;
#pragma unroll
    for (int jj = 0; jj < 8; ++jj) {
      HL r0 = split16(Tt[c + jj][r]);
      HL r1 = split16(Tt[c + 8 + jj][r]);
      h0[jj] = r0.h; l0[jj] = r0.l;
      h1[jj] = r1.h; l1[jj] = r1.l;
    }
    _Float16* dh = Wth + ((size_t)z * EE + n0 + r) * EE + k0 + c;
    _Float16* dl = Wtl + ((size_t)z * EE + n0 + r) * EE + k0 + c;
    *(f16x8*)dh = h0;
    *(f16x8*)(dh + 8) = h1;
    *(f16x8*)dl = l0;
    *(f16x8*)(dl + 8) = l1;
  }
}

// ---------------------------------------------------------------------------
// K_qkv: LDS-staged 3-term f16 MFMA GEMM with register-prefetch pipelining.
// A (=x) is read fp32 and split in-register during staging. Block = 64m x 64n,
// 4 waves stacked in m. q pre-scaled by 0.125. which==2 (V): transpose in LDS,
// store v_t split-f16 [bh][d][si].
__global__ __launch_bounds__(256) void k_qkv_mfma(
    const float* __restrict__ x,
    const _Float16* __restrict__ Wth, const _Float16* __restrict__ Wtl,
    const float* __restrict__ bq, const float* __restrict__ bk,
    const float* __restrict__ bv,
    _Float16* __restrict__ qh, _Float16* __restrict__ ql,
    _Float16* __restrict__ kh, _Float16* __restrict__ kl,
    _Float16* __restrict__ vth, _Float16* __restrict__ vtl) {
  const int which = blockIdx.z;
  const int tid = threadIdx.x;
  const int wave = tid >> 6, lane = tid & 63;
  const int quad = lane >> 4, l16 = lane & 15;
  const int m0 = blockIdx.y * 64;
  const int n0 = blockIdx.x * 64;
  const _Float16* Bh = Wth + (size_t)which * EE * EE;
  const _Float16* Bl = Wtl + (size_t)which * EE * EE;

  __shared__ __align__(16) char smpool[36864];
  _Float16(*LAh)[72] = (_Float16(*)[72])(smpool);
  _Float16(*LAl)[72] = (_Float16(*)[72])(smpool + 9216);
  _Float16(*LBh)[72] = (_Float16(*)[72])(smpool + 18432);
  _Float16(*LBl)[72] = (_Float16(*)[72])(smpool + 27648);
  float(*TR)[68] = (float(*)[68])(smpool);  // reused for V transpose

  const int sr0 = tid >> 3, sc0 = (tid & 7) * 8;
  const int sr1 = sr0 + 32;

  // prefetch stage k0=0: A fp32 (split later), B f16 hi/lo
  float4 rx0a = *(const float4*)(x + (size_t)(m0 + sr0) * EE + sc0);
  float4 rx0b = *(const float4*)(x + (size_t)(m0 + sr0) * EE + sc0 + 4);
  float4 rx1a = *(const float4*)(x + (size_t)(m0 + sr1) * EE + sc0);
  float4 rx1b = *(const float4*)(x + (size_t)(m0 + sr1) * EE + sc0 + 4);
  f16x8 rB0h = *(const f16x8*)(Bh + (size_t)(n0 + sr0) * EE + sc0);
  f16x8 rB0l = *(const f16x8*)(Bl + (size_t)(n0 + sr0) * EE + sc0);
  f16x8 rB1h = *(const f16x8*)(Bh + (size_t)(n0 + sr1) * EE + sc0);
  f16x8 rB1l = *(const f16x8*)(Bl + (size_t)(n0 + sr1) * EE + sc0);

  f32x4 acc[4] = {};
  for (int k0 = 0; k0 < EE; k0 += 64) {
    if (k0) __syncthreads();
    {
      float f0[8] = {rx0a.x, rx0a.y, rx0a.z, rx0a.w,
                     rx0b.x, rx0b.y, rx0b.z, rx0b.w};
      float f1[8] = {rx1a.x, rx1a.y, rx1a.z, rx1a.w,
                     rx1b.x, rx1b.y, rx1b.z, rx1b.w};
      f16x8 h0, l0, h1, l1;
#pragma unroll
      for (int j = 0; j < 8; ++j) {
        HL r0 = split16(f0[j]);
        HL r1 = split16(f1[j]);
        h0[j] = r0.h; l0[j] = r0.l;
        h1[j] = r1.h; l1[j] = r1.l;
      }
      *(f16x8*)&LAh[sr0][sc0] = h0;
      *(f16x8*)&LAl[sr0][sc0] = l0;
      *(f16x8*)&LAh[sr1][sc0] = h1;
      *(f16x8*)&LAl[sr1][sc0] = l1;
    }
    *(f16x8*)&LBh[sr0][sc0] = rB0h;
    *(f16x8*)&LBl[sr0][sc0] = rB0l;
    *(f16x8*)&LBh[sr1][sc0] = rB1h;
    *(f16x8*)&LBl[sr1][sc0] = rB1l;
    __syncthreads();
    if (k0 + 64 < EE) {
      const int kn = k0 + 64;
      rx0a = *(const float4*)(x + (size_t)(m0 + sr0) * EE + kn + sc0);
      rx0b = *(const float4*)(x + (size_t)(m0 + sr0) * EE + kn + sc0 + 4);
      rx1a = *(const float4*)(x + (size_t)(m0 + sr1) * EE + kn + sc0);
      rx1b = *(const float4*)(x + (size_t)(m0 + sr1) * EE + kn + sc0 + 4);
      rB0h = *(const f16x8*)(Bh + (size_t)(n0 + sr0) * EE + kn + sc0);
      rB0l = *(const f16x8*)(Bl + (size_t)(n0 + sr0) * EE + kn + sc0);
      rB1h = *(const f16x8*)(Bh + (size_t)(n0 + sr1) * EE + kn + sc0);
      rB1l = *(const f16x8*)(Bl + (size_t)(n0 + sr1) * EE + kn + sc0);
    }
#pragma unroll
    for (int kk = 0; kk < 64; kk += 32) {
      f16x8 ah = *(const f16x8*)&LAh[wave * 16 + l16][kk + quad * 8];
      f16x8 al = *(const f16x8*)&LAl[wave * 16 + l16][kk + quad * 8];
#pragma unroll
      for (int nt = 0; nt < 4; ++nt) {
        f16x8 bhf = *(const f16x8*)&LBh[nt * 16 + l16][kk + quad * 8];
        f16x8 blf = *(const f16x8*)&LBl[nt * 16 + l16][kk + quad * 8];
        acc[nt] = __builtin_amdgcn_mfma_f32_16x16x32_f16(ah, bhf, acc[nt], 0, 0, 0);
        acc[nt] = __builtin_amdgcn_mfma_f32_16x16x32_f16(ah, blf, acc[nt], 0, 0, 0);
        acc[nt] = __builtin_amdgcn_mfma_f32_16x16x32_f16(al, bhf, acc[nt], 0, 0, 0);
      }
    }
  }
  const float* bias = (which == 0) ? bq : (which == 1) ? bk : bv;
  if (which == 2) {
    // V path: bias-add, transpose via LDS, store split-f16 [bh][d][si]
    __syncthreads();  // main-loop LDS reads done before overwrite
#pragma unroll
    for (int nt = 0; nt < 4; ++nt) {
      const int dcol = nt * 16 + l16;             // d within head
      const float bb = bias[n0 + nt * 16 + l16];  // n0 = head*64
#pragma unroll
      for (int r = 0; r < 4; ++r)
        TR[dcol][wave * 16 + quad * 4 + r] = acc[nt][r] + bb;
    }
    __syncthreads();
    const int d = tid >> 2, cc = (tid & 3) * 16;
    const int bh = (m0 >> 9) * NH + (n0 >> 6);
    const int si0 = m0 & 511;
    f16x8 h0, l0, h1, l1;
#pragma unroll
    for (int jj = 0; jj < 8; ++jj) {
      HL r0 = split16(TR[d][cc + jj]);
      HL r1 = split16(TR[d][cc + 8 + jj]);
      h0[jj] = r0.h; l0[jj] = r0.l;
      h1[jj] = r1.h; l1[jj] = r1.l;
    }
    _Float16* dh = vth + ((size_t)bh * HD + d) * SS + si0 + cc;
    _Float16* dl = vtl + ((size_t)bh * HD + d) * SS + si0 + cc;
    *(f16x8*)dh = h0;
    *(f16x8*)(dh + 8) = h1;
    *(f16x8*)dl = l0;
    *(f16x8*)(dl + 8) = l1;
  } else {
    const float postscale = (which == 0) ? 0.125f : 1.0f;
    const int mbase = m0 + wave * 16 + quad * 4;
#pragma unroll
    for (int nt = 0; nt < 4; ++nt) {
      const int col = n0 + nt * 16 + l16;
      const float bb = bias[col];
      const int hh = col >> 6, d = col & 63;
#pragma unroll
      for (int r = 0; r < 4; ++r) {
        const int mm = mbase + r;
        const int b_ = mm >> 9, si = mm & 511;
        const size_t idx = (((size_t)(b_ * NH + hh)) * SS + si) * HD + d;
        const float val = (acc[nt][r] + bb) * postscale;
        HL sp = split16(val);
        (which ? kh : qh)[idx] = sp.h;
        (which ? kl : ql)[idx] = sp.l;
      }
    }
  }
}

// ---------------------------------------------------------------------------
// K_scores: s = clip(q.k^T, -15, 15) via 3-term f16 MFMA (q pre-scaled).
// LDS-staged. grid (8 jT, 8 iT, 32 bh), block 256 (4 waves stacked in m).
__global__ __launch_bounds__(256) void k_scores_mfma(
    const _Float16* __restrict__ qh, const _Float16* __restrict__ ql,
    const _Float16* __restrict__ kh, const _Float16* __restrict__ kl,
    float* __restrict__ s) {
  const int bh = blockIdx.z;
  const int i0 = blockIdx.y * 64, j0 = blockIdx.x * 64;
  const int tid = threadIdx.x;
  const int wave = tid >> 6, lane = tid & 63;
  const int quad = lane >> 4, l16 = lane & 15;

  __shared__ _Float16 Qh[64][72], Ql[64][72], Kh[64][72], Kl[64][72];
  const int r = tid >> 2, c = (tid & 3) * 16;
  {
    const size_t qoff = ((size_t)bh * SS + i0 + r) * HD + c;
    const size_t koff = ((size_t)bh * SS + j0 + r) * HD + c;
    *(f16x8*)&Qh[r][c] = *(const f16x8*)(qh + qoff);
    *(f16x8*)&Qh[r][c + 8] = *(const f16x8*)(qh + qoff + 8);
    *(f16x8*)&Ql[r][c] = *(const f16x8*)(ql + qoff);
    *(f16x8*)&Ql[r][c + 8] = *(const f16x8*)(ql + qoff + 8);
    *(f16x8*)&Kh[r][c] = *(const f16x8*)(kh + koff);
    *(f16x8*)&Kh[r][c + 8] = *(const f16x8*)(kh + koff + 8);
    *(f16x8*)&Kl[r][c] = *(const f16x8*)(kl + koff);
    *(f16x8*)&Kl[r][c + 8] = *(const f16x8*)(kl + koff + 8);
  }
  __syncthreads();

  f16x8 a_hi[2], a_lo[2];
#pragma unroll
  for (int ks = 0; ks < 2; ++ks) {
    a_hi[ks] = *(const f16x8*)&Qh[wave * 16 + l16][ks * 32 + quad * 8];
    a_lo[ks] = *(const f16x8*)&Ql[wave * 16 + l16][ks * 32 + quad * 8];
  }
  f32x4 acc[4] = {};
#pragma unroll
  for (int ks = 0; ks < 2; ++ks) {
#pragma unroll
    for (int t = 0; t < 4; ++t) {
      f16x8 b_hi = *(const f16x8*)&Kh[t * 16 + l16][ks * 32 + quad * 8];
      f16x8 b_lo = *(const f16x8*)&Kl[t * 16 + l16][ks * 32 + quad * 8];
      acc[t] = __builtin_amdgcn_mfma_f32_16x16x32_f16(a_hi[ks], b_hi,
                                                      acc[t], 0, 0, 0);
      acc[t] = __builtin_amdgcn_mfma_f32_16x16x32_f16(a_hi[ks], b_lo,
                                                      acc[t], 0, 0, 0);
      acc[t] = __builtin_amdgcn_mfma_f32_16x16x32_f16(a_lo[ks], b_hi,
                                                      acc[t], 0, 0, 0);
    }
  }
  float* sb = s + (size_t)bh * SS * SS;
#pragma unroll
  for (int t = 0; t < 4; ++t) {
#pragma unroll
    for (int r2 = 0; r2 < 4; ++r2) {
      float val = clampf(acc[t][r2], -15.0f, 15.0f);  // inputs finite
      sb[(size_t)(i0 + wave * 16 + quad * 4 + r2) * SS + j0 + t * 16 + l16] = val;
    }
  }
}

// ---------------------------------------------------------------------------
// K_rowstat: per-row fused ma + autopoietic transform (one wave per row,
// 2048 blocks x 64 -- per-row rowred stores, NO atomics).
__global__ __launch_bounds__(64) void k_rowstat(
    const float* __restrict__ s, const float* __restrict__ T,
    float* __restrict__ ma, float* __restrict__ t_un,
    float* __restrict__ rowred) {
  const int row = blockIdx.x;  // b*S + i
  const int b_ = row >> 9, i = row & 511;
  const int lane = threadIdx.x;

  float4 a0 = {0.f, 0.f, 0.f, 0.f}, a1 = {0.f, 0.f, 0.f, 0.f};
#pragma unroll
  for (int hh = 0; hh < NH; ++hh) {
    const float4* p = reinterpret_cast<const float4*>(
                          s + (((size_t)(b_ * NH + hh) * SS) + i) * SS) +
                      lane * 2;
    float4 u0 = p[0], u1 = p[1];
    a0.x += u0.x; a0.y += u0.y; a0.z += u0.z; a0.w += u0.w;
    a1.x += u1.x; a1.y += u1.y; a1.z += u1.z; a1.w += u1.w;
  }
  float m[8] = {a0.x * 0.125f, a0.y * 0.125f, a0.z * 0.125f, a0.w * 0.125f,
                a1.x * 0.125f, a1.y * 0.125f, a1.z * 0.125f, a1.w * 0.125f};
  {
    float4* mp = reinterpret_cast<float4*>(ma + ((size_t)b_ * SS + i) * SS) +
                 lane * 2;
    float4 w0 = {m[0], m[1], m[2], m[3]}, w1v = {m[4], m[5], m[6], m[7]};
    mp[0] = w0;
    mp[1] = w1v;
  }
  float sma = 0.f, sma2 = 0.f, mabs = 0.f;
#pragma unroll
  for (int e = 0; e < 8; ++e) {
    sma += m[e];
    sma2 += m[e] * m[e];
    mabs = fmaxf(mabs, fabsf(m[e]));
  }
  sma = waveRedSum(sma);
  sma2 = waveRedSum(sma2);
  mabs = waveRedMax(mabs);

  float ex[8], esum = 0.f;
#pragma unroll
  for (int e = 0; e < 8; ++e) {
    ex[e] = expf(clampf(m[e], -10.f, 10.f));
    esum += ex[e];
  }
  esum = waveRedSum(esum);
  float inv = 1.0f / esum;
  float Hv[8], sH = 0.f;
#pragma unroll
  for (int e = 0; e < 8; ++e) {
    float p = ex[e] * inv;
    Hv[e] = -p * logf(p + 1e-6f);
    sH += Hv[e];
  }
  sH = waveRedSum(sH);

  float fx[8], fsum = 0.f;
#pragma unroll
  for (int e = 0; e < 8; ++e) {
    fx[e] = expf(3.0f * Hv[e]);
    fsum += fx[e];
  }
  fsum = waveRedSum(fsum);
  float finv = 1.0f / fsum;

  float t[8], st = 0.f, st2 = 0.f;
#pragma unroll
  for (int e = 0; e < 8; ++e) {
    float sa = clampf(m[e], -8.f, 8.f) * 0.05f;
    float pos = (sa + 0.4f) * ((float)NTAB / 0.8f);
    int idx = (int)pos;
    idx = idx < 0 ? 0 : (idx > NTAB - 1 ? NTAB - 1 : idx);
    float frac = pos - (float)idx;
    float g0 = T[idx], g1 = T[idx + 1];
    float sig = g0 + (g1 - g0) * frac;
    t[e] = sig * fx[e] * finv;
    st += t[e];
    st2 += t[e] * t[e];
  }
  st = waveRedSum(st);
  st2 = waveRedSum(st2);
  {
    float4* tp = reinterpret_cast<float4*>(t_un + ((size_t)b_ * SS + i) * SS) +
                 lane * 2;
    float4 w0 = {t[0], t[1], t[2], t[3]}, w1v = {t[4], t[5], t[6], t[7]};
    tp[0] = w0;
    tp[1] = w1v;
  }
  if (lane == 0) {
    float* rp = rowred + (size_t)row * 8;
    rp[0] = sma; rp[1] = sma2; rp[2] = mabs;
    rp[3] = st;  rp[4] = st2;  rp[5] = sH;
  }
}

// ---------------------------------------------------------------------------
// K_consts: reduce per-row partials -> per-batch blend constants.
__global__ __launch_bounds__(256) void k_consts(
    const float* __restrict__ rowred, float* __restrict__ cst) {
  const int b_ = blockIdx.x;
  const int tid = threadIdx.x;
  __shared__ float red[4];
  const float* r0 = rowred + ((size_t)b_ * SS + tid * 2) * 8;
  const float* r1 = r0 + 8;
  float sma = blockRedSum(r0[0] + r1[0], red);
  float sma2 = blockRedSum(r0[1] + r1[1], red);
  float mabs = blockRedMax(fmaxf(r0[2], r1[2]), red);
  float st = blockRedSum(r0[3] + r1[3], red);
  float st2 = blockRedSum(r0[4] + r1[4], red);
  float sH = blockRedSum(r0[5] + r1[5], red);
  if (tid == 0) {
    const float N = (float)(SS * SS);
    float eo = sqrtf(sma2) + 1e-4f;
    float et = sqrtf(st2) + 1e-4f;
    float r = clampf(eo / et, 0.8f, 1.2f);
    float tmean = r * st / N;
    float om = sma / N;
    float vart = r * r * fmaxf(st2 / N - (st / N) * (st / N), 0.f);
    float tstd = sqrtf(fmaxf(vart, 0.01f));
    float varo = fmaxf(sma2 / N - om * om, 0.f);
    float ostd = sqrtf(fmaxf(varo, 0.01f));
    float gd = clampf(ostd / tstd, 0.8f, 1.2f);
    float ar = clampf(mabs, 1.f, 10.f);
    float sm = clampf(0.3f / log1pf(ar), 0.1f, 0.5f);
    float ent = sH / N;
    float ne = ent / logf((float)SS);
    float rr = 0.4f * (1.f - clampf(ne, 0.f, 0.4f));
    float G = sm * gd;
    cst[b_ * 4 + 0] = rr * (1.f - G) * tmean;  // c0
    cst[b_ * 4 + 1] = rr * G * r;              // c1 (multiplies t_un)
    cst[b_ * 4 + 2] = rr;                      // c2 (multiplies ma)
  }
}

// ---------------------------------------------------------------------------
// K_av_fused: out = softmax(blend(s)) @ v with NO materialized p.
// m-tile = 32 rows -> grid (16 mb, 32 bh). Stage threads (tid<128) compute
// unnormalized e' = exp(blend)*2^-16, split into LDS, accumulate Z partials.
__global__ __launch_bounds__(256) void k_av_fused(
    const float* __restrict__ s, const float* __restrict__ ma,
    const float* __restrict__ t_un, const float* __restrict__ cst,
    const float* __restrict__ tau, const _Float16* __restrict__ vth,
    const _Float16* __restrict__ vtl, _Float16* __restrict__ oh,
    _Float16* __restrict__ ol) {
  const int bh = blockIdx.y;
  const int b_ = bh >> 3, hh = bh & 7;
  const int m0 = blockIdx.x * 32;
  const int tid = threadIdx.x;
  const int wave = tid >> 6, lane = tid & 63;
  const int quad = lane >> 4, l16 = lane & 15;

  const float c0 = cst[b_ * 4 + 0], c1 = cst[b_ * 4 + 1], c2 = cst[b_ * 4 + 2];
  const float itau = 1.0f / tau[0];

  __shared__ _Float16 Ph[32][40], Pl[32][40];
  __shared__ float Zp[32][4];

  const bool stager = (tid < 128);
  const int srow = tid >> 2;          // 0..31 valid when stager
  const int ci = tid & 3;
  const int schunk = ci * 8;
  const size_t sbase = ((size_t)bh * SS + m0 + (srow & 31)) * SS + schunk;
  const size_t mbase = ((size_t)b_ * SS + m0 + (srow & 31)) * SS + schunk;

  float4 sv0, sv1, mv0, mv1, tv0, tv1;
  if (stager) {
    sv0 = *(const float4*)(s + sbase);
    sv1 = *(const float4*)(s + sbase + 4);
    mv0 = *(const float4*)(ma + mbase);
    mv1 = *(const float4*)(ma + mbase + 4);
    tv0 = *(const float4*)(t_un + mbase);
    tv1 = *(const float4*)(t_un + mbase + 4);
  }

  float zpart = 0.f;
  f32x4 acc[2] = {};
  for (int k0 = 0; k0 < SS; k0 += 32) {
    if (k0) __syncthreads();  // prior-stage LDS reads done
    if (stager) {
      float svv[8] = {sv0.x, sv0.y, sv0.z, sv0.w, sv1.x, sv1.y, sv1.z, sv1.w};
      float mvv[8] = {mv0.x, mv0.y, mv0.z, mv0.w, mv1.x, mv1.y, mv1.z, mv1.w};
      float tvv[8] = {tv0.x, tv0.y, tv0.z, tv0.w, tv1.x, tv1.y, tv1.z, tv1.w};
      f16x8 hv, lv;
#pragma unroll
      for (int j = 0; j < 8; ++j) {
        float vv = (svv[j] + c0 + c1 * tvv[j] - c2 * mvv[j]) * itau;
        float e = expf(vv) * 1.52587890625e-05f;  // * 2^-16
        zpart += e;
        HL r = split16(e);
        hv[j] = r.h;
        lv[j] = r.l;
      }
      *(f16x8*)&Ph[srow][schunk] = hv;
      *(f16x8*)&Pl[srow][schunk] = lv;
    }
    __syncthreads();
    if (stager && k0 + 32 < SS) {
      sv0 = *(const float4*)(s + sbase + k0 + 32);
      sv1 = *(const float4*)(s + sbase + k0 + 36);
      mv0 = *(const float4*)(ma + mbase + k0 + 32);
      mv1 = *(const float4*)(ma + mbase + k0 + 36);
      tv0 = *(const float4*)(t_un + mbase + k0 + 32);
      tv1 = *(const float4*)(t_un + mbase + k0 + 36);
    }
    const size_t boff = ((size_t)bh * HD + wave * 16 + l16) * SS + k0 + quad * 8;
    f16x8 bh_ = *(const f16x8*)(vth + boff);
    f16x8 bl_ = *(const f16x8*)(vtl + boff);
#pragma unroll
    for (int mt = 0; mt < 2; ++mt) {
      f16x8 ah = *(const f16x8*)&Ph[mt * 16 + l16][quad * 8];
      f16x8 al = *(const f16x8*)&Pl[mt * 16 + l16][quad * 8];
      acc[mt] = __builtin_amdgcn_mfma_f32_16x16x32_f16(ah, bh_, acc[mt], 0, 0, 0);
      acc[mt] = __builtin_amdgcn_mfma_f32_16x16x32_f16(ah, bl_, acc[mt], 0, 0, 0);
      acc[mt] = __builtin_amdgcn_mfma_f32_16x16x32_f16(al, bh_, acc[mt], 0, 0, 0);
    }
  }
  __syncthreads();
  if (stager) Zp[srow][ci] = zpart;
  __syncthreads();
#pragma unroll
  for (int mt = 0; mt < 2; ++mt) {
#pragma unroll
    for (int r = 0; r < 4; ++r) {
      const int lr = mt * 16 + quad * 4 + r;  // local row 0..31
      const float Z = Zp[lr][0] + Zp[lr][1] + Zp[lr][2] + Zp[lr][3];
      const float oV = acc[mt][r] / Z;
      const int si = m0 + lr;
      const size_t idx =
          ((size_t)(b_ * SS + si)) * EE + hh * HD + wave * 16 + l16;
      HL sp = split16(oV);
      oh[idx] = sp.h;
      ol[idx] = sp.l;
    }
  }
}

// ---------------------------------------------------------------------------
// K_out: LDS-staged 3-term f16 MFMA GEMM with register-prefetch pipelining,
// fp32 output + bias. grid (8 nb, 32 mb), block 256.
__global__ __launch_bounds__(256) void k_out_mfma(
    const _Float16* __restrict__ oh, const _Float16* __restrict__ ol,
    const _Float16* __restrict__ Wth, const _Float16* __restrict__ Wtl,
    const float* __restrict__ bo, float* __restrict__ out) {
  const int tid = threadIdx.x;
  const int wave = tid >> 6, lane = tid & 63;
  const int quad = lane >> 4, l16 = lane & 15;
  const int m0 = blockIdx.y * 64;
  const int n0 = blockIdx.x * 64;
  const _Float16* Bh = Wth + (size_t)3 * EE * EE;  // Wo^T
  const _Float16* Bl = Wtl + (size_t)3 * EE * EE;

  __shared__ _Float16 LAh[64][72], LAl[64][72], LBh[64][72], LBl[64][72];

  const int sr0 = tid >> 3, sc0 = (tid & 7) * 8;
  const int sr1 = sr0 + 32;

  f16x8 rA0h = *(const f16x8*)(oh + (size_t)(m0 + sr0) * EE + sc0);
  f16x8 rA0l = *(const f16x8*)(ol + (size_t)(m0 + sr0) * EE + sc0);
  f16x8 rB0h = *(const f16x8*)(Bh + (size_t)(n0 + sr0) * EE + sc0);
  f16x8 rB0l = *(const f16x8*)(Bl + (size_t)(n0 + sr0) * EE + sc0);
  f16x8 rA1h = *(const f16x8*)(oh + (size_t)(m0 + sr1) * EE + sc0);
  f16x8 rA1l = *(const f16x8*)(ol + (size_t)(m0 + sr1) * EE + sc0);
  f16x8 rB1h = *(const f16x8*)(Bh + (size_t)(n0 + sr1) * EE + sc0);
  f16x8 rB1l = *(const f16x8*)(Bl + (size_t)(n0 + sr1) * EE + sc0);

  f32x4 acc[4] = {};
  for (int k0 = 0; k0 < EE; k0 += 64) {
    if (k0) __syncthreads();
    *(f16x8*)&LAh[sr0][sc0] = rA0h;
    *(f16x8*)&LAl[sr0][sc0] = rA0l;
    *(f16x8*)&LBh[sr0][sc0] = rB0h;
    *(f16x8*)&LBl[sr0][sc0] = rB0l;
    *(f16x8*)&LAh[sr1][sc0] = rA1h;
    *(f16x8*)&LAl[sr1][sc0] = rA1l;
    *(f16x8*)&LBh[sr1][sc0] = rB1h;
    *(f16x8*)&LBl[sr1][sc0] = rB1l;
    __syncthreads();
    if (k0 + 64 < EE) {
      const int kn = k0 + 64;
      rA0h = *(const f16x8*)(oh + (size_t)(m0 + sr0) * EE + kn + sc0);
      rA0l = *(const f16x8*)(ol + (size_t)(m0 + sr0) * EE + kn + sc0);
      rB0h = *(const f16x8*)(Bh + (size_t)(n0 + sr0) * EE + kn + sc0);
      rB0l = *(const f16x8*)(Bl + (size_t)(n0 + sr0) * EE + kn + sc0);
      rA1h = *(const f16x8*)(oh + (size_t)(m0 + sr1) * EE + kn + sc0);
      rA1l = *(const f16x8*)(ol + (size_t)(m0 + sr1) * EE + kn + sc0);
      rB1h = *(const f16x8*)(Bh + (size_t)(n0 + sr1) * EE + kn + sc0);
      rB1l = *(const f16x8*)(Bl + (size_t)(n0 + sr1) * EE + kn + sc0);
    }
#pragma unroll
    for (int kk = 0; kk < 64; kk += 32) {
      f16x8 ah = *(const f16x8*)&LAh[wave * 16 + l16][kk + quad * 8];
      f16x8 al = *(const f16x8*)&LAl[wave * 16 + l16][kk + quad * 8];
#pragma unroll
      for (int nt = 0; nt < 4; ++nt) {
        f16x8 bhf = *(const f16x8*)&LBh[nt * 16 + l16][kk + quad * 8];
        f16x8 blf = *(const f16x8*)&LBl[nt * 16 + l16][kk + quad * 8];
        acc[nt] = __builtin_amdgcn_mfma_f32_16x16x32_f16(ah, bhf, acc[nt], 0, 0, 0);
        acc[nt] = __builtin_amdgcn_mfma_f32_16x16x32_f16(ah, blf, acc[nt], 0, 0, 0);
        acc[nt] = __builtin_amdgcn_mfma_f32_16x16x32_f16(al, bhf, acc[nt], 0, 0, 0);
      }
    }
  }
  const int mbase = m0 + wave * 16 + quad * 4;
#pragma unroll
  for (int nt = 0; nt < 4; ++nt) {
    const int col = n0 + nt * 16 + l16;
    const float bb = bo[col];
#pragma unroll
    for (int r = 0; r < 4; ++r) {
      const int m = mbase + r;
      out[(size_t)m * EE + col] = acc[nt][r] + bb;
    }
  }
}

// ---------------------------------------------------------------------------
extern "C" void kernel_launch(void* const* d_in, const int* in_sizes, int n_in,
                              void* d_out, int out_size, void* d_ws,
                              size_t ws_size, hipStream_t stream) {
  const float* x = (const float*)d_in[0];
  const float* Wq = (const float*)d_in[1];
  const float* bq = (const float*)d_in[2];
  const float* Wk = (const float*)d_in[3];
  const float* bk = (const float*)d_in[4];
  const float* Wv = (const float*)d_in[5];
  const float* bv = (const float*)d_in[6];
  const float* Wo = (const float*)d_in[7];
  const float* bo = (const float*)d_in[8];
  const float* w1 = (const float*)d_in[9];
  const float* b1 = (const float*)d_in[10];
  const float* w2 = (const float*)d_in[11];
  const float* b2 = (const float*)d_in[12];
  const float* tau = (const float*)d_in[13];
  float* out = (float*)d_out;

  const size_t NX = (size_t)2048 * EE;           // 1M elems (o)
  const size_t NW = (size_t)4 * EE * EE;         // 1M elems (4 W's)
  const size_t NQK = (size_t)BB * NH * SS * HD;  // 1M elems
  const size_t NS = (size_t)BB * NH * SS * SS;   // 8.39M elems

  _Float16* Wth = (_Float16*)d_ws;
  _Float16* Wtl = Wth + NW;
  _Float16* qh = Wtl + NW;
  _Float16* ql = qh + NQK;
  _Float16* kh = ql + NQK;
  _Float16* kl = kh + NQK;
  _Float16* vth = kl + NQK;
  _Float16* vtl = vth + NQK;
  _Float16* oh = vtl + NQK;
  _Float16* ol = oh + NX;
  float* s = (float*)(ol + NX);
  float* ma = s + NS;
  float* t_un = ma + (size_t)BB * SS * SS;
  float* T = t_un + (size_t)BB * SS * SS;
  float* rowred = T + 8192;            // 2048*8
  float* cst = rowred + 2048 * 8;      // 16

  k_prep<<<273, 256, 0, stream>>>(w1, b1, w2, b2, T, Wq, Wk, Wv, Wo, Wth, Wtl);
  k_qkv_mfma<<<dim3(8, 32, 3), 256, 0, stream>>>(x, Wth, Wtl, bq, bk, bv, qh,
                                                 ql, kh, kl, vth, vtl);
  k_scores_mfma<<<dim3(8, 8, 32), 256, 0, stream>>>(qh, ql, kh, kl, s);
  k_rowstat<<<2048, 64, 0, stream>>>(s, T, ma, t_un, rowred);
  k_consts<<<4, 256, 0, stream>>>(rowred, cst);
  k_av_fused<<<dim3(16, 32), 256, 0, stream>>>(s, ma, t_un, cst, tau, vth, vtl,
                                               oh, ol);
  k_out_mfma<<<dim3(8, 32), 256, 0, stream>>>(oh, ol, Wth, Wtl, bo, out);
}

// Round 14
// 159.246 us; speedup vs baseline: 1.7360x; 1.0345x over previous
//
#include <hip/hip_runtime.h>
#include <math.h>

// Problem constants (fixed by setup_inputs)
#define BB 4
#define SS 512
#define EE 512
#define NH 8
#define HD 64
#define NC 128
#define NTAB 4096  // table intervals over sa in [-0.4, 0.4]

typedef _Float16 f16x8 __attribute__((ext_vector_type(8)));
typedef float f32x4 __attribute__((ext_vector_type(4)));

struct HL { _Float16 h, l; };

__device__ __forceinline__ float clampf(float v, float lo, float hi) {
  return fminf(fmaxf(v, lo), hi);
}
__device__ __forceinline__ HL split16(float x) {
  HL r;
  r.h = (_Float16)x;
  r.l = (_Float16)(x - (float)r.h);
  return r;
}

__device__ __forceinline__ float waveRedSum(float v) {
#pragma unroll
  for (int o = 32; o; o >>= 1) v += __shfl_xor(v, o);
  return v;
}
__device__ __forceinline__ float waveRedMax(float v) {
#pragma unroll
  for (int o = 32; o; o >>= 1) v = fmaxf(v, __shfl_xor(v, o));
  return v;
}
// blockDim.x == 256 (4 waves) assumed
__device__ __forceinline__ float blockRedSum(float v, float* red) {
  int tid = threadIdx.x;
  v = waveRedSum(v);
  __syncthreads();
  if ((tid & 63) == 0) red[tid >> 6] = v;
  __syncthreads();
  return red[0] + red[1] + red[2] + red[3];
}
__device__ __forceinline__ float blockRedMax(float v, float* red) {
  int tid = threadIdx.x;
  v = waveRedMax(v);
  __syncthreads();
  if ((tid & 63) == 0) red[tid >> 6] = v;
  __syncthreads();
  return fmaxf(fmaxf(red[0], red[1]), fmaxf(red[2], red[3]));
}

// ---------------------------------------------------------------------------
// K_prep: transpose+split the 4 weight matrices (table moved into k_qkv).
// 256 blocks.
__global__ __launch_bounds__(256) void k_prep(
    const float* __restrict__ Wq, const float* __restrict__ Wk,
    const float* __restrict__ Wv, const float* __restrict__ Wo,
    _Float16* __restrict__ Wth, _Float16* __restrict__ Wtl) {
  const int j = blockIdx.x;         // [0,256)
  const int tid = threadIdx.x;
  const int z = j >> 6;             // matrix
  const int rem = j & 63;
  const int k0 = (rem & 7) * 64, n0 = (rem >> 3) * 64;
  const float* W = (z == 0) ? Wq : (z == 1) ? Wk : (z == 2) ? Wv : Wo;
  __shared__ float Tt[64][68];
  const int r = tid >> 2, c = (tid & 3) * 16;
#pragma unroll
  for (int jj = 0; jj < 16; jj += 4)
    *(float4*)&Tt[r][c + jj] =
        *(const float4*)(W + (size_t)(k0 + r) * EE + n0 + c + jj);
  __syncthreads();
  f16x8 h0, l0, h1, l1;
#pragma unroll
  for (int jj = 0; jj < 8; ++jj) {
    HL r0 = split16(Tt[c + jj][r]);
    HL r1 = split16(Tt[c + 8 + jj][r]);
    h0[jj] = r0.h; l0[jj] = r0.l;
    h1[jj] = r1.h; l1[jj] = r1.l;
  }
  _Float16* dh = Wth + ((size_t)z * EE + n0 + r) * EE + k0 + c;
  _Float16* dl = Wtl + ((size_t)z * EE + n0 + r) * EE + k0 + c;
  *(f16x8*)dh = h0;
  *(f16x8*)(dh + 8) = h1;
  *(f16x8*)dl = l0;
  *(f16x8*)(dl + 8) = l1;
}

// ---------------------------------------------------------------------------
// K_qkv: LDS-staged 3-term f16 MFMA GEMM with register-prefetch pipelining.
// A (=x) read fp32, split in-register during staging. Block = 64m x 64n,
// 4 waves stacked in m. q pre-scaled by 0.125. which==2 (V): transpose in
// LDS, store v_t split-f16 [bh][d][si]. Blocks (x==0, y<17, which==0) also
// tabulate the sigmoid table T (consumed by k_rowstat, 2 kernels later).
__global__ __launch_bounds__(256) void k_qkv_mfma(
    const float* __restrict__ x,
    const _Float16* __restrict__ Wth, const _Float16* __restrict__ Wtl,
    const float* __restrict__ bq, const float* __restrict__ bk,
    const float* __restrict__ bv, const float* __restrict__ w1,
    const float* __restrict__ b1, const float* __restrict__ w2,
    const float* __restrict__ b2, float* __restrict__ T,
    _Float16* __restrict__ qh, _Float16* __restrict__ ql,
    _Float16* __restrict__ kh, _Float16* __restrict__ kl,
    _Float16* __restrict__ vth, _Float16* __restrict__ vtl) {
  const int which = blockIdx.z;
  const int tid = threadIdx.x;
  const int wave = tid >> 6, lane = tid & 63;
  const int quad = lane >> 4, l16 = lane & 15;
  const int m0 = blockIdx.y * 64;
  const int n0 = blockIdx.x * 64;
  const _Float16* Bh = Wth + (size_t)which * EE * EE;
  const _Float16* Bl = Wtl + (size_t)which * EE * EE;

  __shared__ __align__(16) char smpool[36864];
  _Float16(*LAh)[72] = (_Float16(*)[72])(smpool);
  _Float16(*LAl)[72] = (_Float16(*)[72])(smpool + 9216);
  _Float16(*LBh)[72] = (_Float16(*)[72])(smpool + 18432);
  _Float16(*LBl)[72] = (_Float16(*)[72])(smpool + 27648);
  float(*TR)[68] = (float(*)[68])(smpool);  // reused for V transpose

  const int sr0 = tid >> 3, sc0 = (tid & 7) * 8;
  const int sr1 = sr0 + 32;

  // prefetch stage k0=0: A fp32 (split later), B f16 hi/lo
  float4 rx0a = *(const float4*)(x + (size_t)(m0 + sr0) * EE + sc0);
  float4 rx0b = *(const float4*)(x + (size_t)(m0 + sr0) * EE + sc0 + 4);
  float4 rx1a = *(const float4*)(x + (size_t)(m0 + sr1) * EE + sc0);
  float4 rx1b = *(const float4*)(x + (size_t)(m0 + sr1) * EE + sc0 + 4);
  f16x8 rB0h = *(const f16x8*)(Bh + (size_t)(n0 + sr0) * EE + sc0);
  f16x8 rB0l = *(const f16x8*)(Bl + (size_t)(n0 + sr0) * EE + sc0);
  f16x8 rB1h = *(const f16x8*)(Bh + (size_t)(n0 + sr1) * EE + sc0);
  f16x8 rB1l = *(const f16x8*)(Bl + (size_t)(n0 + sr1) * EE + sc0);

  f32x4 acc[4] = {};
  for (int k0 = 0; k0 < EE; k0 += 64) {
    if (k0) __syncthreads();
    {
      float f0[8] = {rx0a.x, rx0a.y, rx0a.z, rx0a.w,
                     rx0b.x, rx0b.y, rx0b.z, rx0b.w};
      float f1[8] = {rx1a.x, rx1a.y, rx1a.z, rx1a.w,
                     rx1b.x, rx1b.y, rx1b.z, rx1b.w};
      f16x8 h0, l0, h1, l1;
#pragma unroll
      for (int j = 0; j < 8; ++j) {
        HL r0 = split16(f0[j]);
        HL r1 = split16(f1[j]);
        h0[j] = r0.h; l0[j] = r0.l;
        h1[j] = r1.h; l1[j] = r1.l;
      }
      *(f16x8*)&LAh[sr0][sc0] = h0;
      *(f16x8*)&LAl[sr0][sc0] = l0;
      *(f16x8*)&LAh[sr1][sc0] = h1;
      *(f16x8*)&LAl[sr1][sc0] = l1;
    }
    *(f16x8*)&LBh[sr0][sc0] = rB0h;
    *(f16x8*)&LBl[sr0][sc0] = rB0l;
    *(f16x8*)&LBh[sr1][sc0] = rB1h;
    *(f16x8*)&LBl[sr1][sc0] = rB1l;
    __syncthreads();
    if (k0 + 64 < EE) {
      const int kn = k0 + 64;
      rx0a = *(const float4*)(x + (size_t)(m0 + sr0) * EE + kn + sc0);
      rx0b = *(const float4*)(x + (size_t)(m0 + sr0) * EE + kn + sc0 + 4);
      rx1a = *(const float4*)(x + (size_t)(m0 + sr1) * EE + kn + sc0);
      rx1b = *(const float4*)(x + (size_t)(m0 + sr1) * EE + kn + sc0 + 4);
      rB0h = *(const f16x8*)(Bh + (size_t)(n0 + sr0) * EE + kn + sc0);
      rB0l = *(const f16x8*)(Bl + (size_t)(n0 + sr0) * EE + kn + sc0);
      rB1h = *(const f16x8*)(Bh + (size_t)(n0 + sr1) * EE + kn + sc0);
      rB1l = *(const f16x8*)(Bl + (size_t)(n0 + sr1) * EE + kn + sc0);
    }
#pragma unroll
    for (int kk = 0; kk < 64; kk += 32) {
      f16x8 ah = *(const f16x8*)&LAh[wave * 16 + l16][kk + quad * 8];
      f16x8 al = *(const f16x8*)&LAl[wave * 16 + l16][kk + quad * 8];
#pragma unroll
      for (int nt = 0; nt < 4; ++nt) {
        f16x8 bhf = *(const f16x8*)&LBh[nt * 16 + l16][kk + quad * 8];
        f16x8 blf = *(const f16x8*)&LBl[nt * 16 + l16][kk + quad * 8];
        acc[nt] = __builtin_amdgcn_mfma_f32_16x16x32_f16(ah, bhf, acc[nt], 0, 0, 0);
        acc[nt] = __builtin_amdgcn_mfma_f32_16x16x32_f16(ah, blf, acc[nt], 0, 0, 0);
        acc[nt] = __builtin_amdgcn_mfma_f32_16x16x32_f16(al, bhf, acc[nt], 0, 0, 0);
      }
    }
  }
  const float* bias = (which == 0) ? bq : (which == 1) ? bk : bv;
  if (which == 2) {
    // V path: bias-add, transpose via LDS, store split-f16 [bh][d][si]
    __syncthreads();  // main-loop LDS reads done before overwrite
#pragma unroll
    for (int nt = 0; nt < 4; ++nt) {
      const int dcol = nt * 16 + l16;             // d within head
      const float bb = bias[n0 + nt * 16 + l16];  // n0 = head*64
#pragma unroll
      for (int r = 0; r < 4; ++r)
        TR[dcol][wave * 16 + quad * 4 + r] = acc[nt][r] + bb;
    }
    __syncthreads();
    const int d = tid >> 2, cc = (tid & 3) * 16;
    const int bh = (m0 >> 9) * NH + (n0 >> 6);
    const int si0 = m0 & 511;
    f16x8 h0, l0, h1, l1;
#pragma unroll
    for (int jj = 0; jj < 8; ++jj) {
      HL r0 = split16(TR[d][cc + jj]);
      HL r1 = split16(TR[d][cc + 8 + jj]);
      h0[jj] = r0.h; l0[jj] = r0.l;
      h1[jj] = r1.h; l1[jj] = r1.l;
    }
    _Float16* dh = vth + ((size_t)bh * HD + d) * SS + si0 + cc;
    _Float16* dl = vtl + ((size_t)bh * HD + d) * SS + si0 + cc;
    *(f16x8*)dh = h0;
    *(f16x8*)(dh + 8) = h1;
    *(f16x8*)dl = l0;
    *(f16x8*)(dl + 8) = l1;
  } else {
    const float postscale = (which == 0) ? 0.125f : 1.0f;
    const int mbase = m0 + wave * 16 + quad * 4;
#pragma unroll
    for (int nt = 0; nt < 4; ++nt) {
      const int col = n0 + nt * 16 + l16;
      const float bb = bias[col];
      const int hh = col >> 6, d = col & 63;
#pragma unroll
      for (int r = 0; r < 4; ++r) {
        const int mm = mbase + r;
        const int b_ = mm >> 9, si = mm & 511;
        const size_t idx = (((size_t)(b_ * NH + hh)) * SS + si) * HD + d;
        const float val = (acc[nt][r] + bb) * postscale;
        HL sp = split16(val);
        (which ? kh : qh)[idx] = sp.h;
        (which ? kl : ql)[idx] = sp.l;
      }
    }
    // sigmoid-table side job: 17 q-blocks tabulate T (used by k_rowstat)
    if (which == 0 && blockIdx.x == 0 && blockIdx.y < 17) {
      int idx = blockIdx.y * 256 + tid;
      if (idx <= NTAB) {
        float sa = -0.4f + (float)idx * (0.8f / (float)NTAB);
        float ap = 0.f;
#pragma unroll 4
        for (int c = 0; c < NC; ++c) {
          float h = fminf(fmaxf(sa * w1[c] + b1[c], 0.f), 5.f);
          ap += h * w2[c];
        }
        ap = clampf(ap + b2[0], -5.f, 5.f);
        float tay = clampf(1.0f + 0.05f * (ap * 50.0f), 0.5f, 1.5f);
        T[idx] = 1.0f / (1.0f + expf(-tay));
      }
    }
  }
}

// ---------------------------------------------------------------------------
// K_scores: s = clip(q.k^T, -15, 15) via 3-term f16 MFMA (q pre-scaled).
// LDS-staged. grid (8 jT, 8 iT, 32 bh), block 256 (4 waves stacked in m).
__global__ __launch_bounds__(256) void k_scores_mfma(
    const _Float16* __restrict__ qh, const _Float16* __restrict__ ql,
    const _Float16* __restrict__ kh, const _Float16* __restrict__ kl,
    float* __restrict__ s) {
  const int bh = blockIdx.z;
  const int i0 = blockIdx.y * 64, j0 = blockIdx.x * 64;
  const int tid = threadIdx.x;
  const int wave = tid >> 6, lane = tid & 63;
  const int quad = lane >> 4, l16 = lane & 15;

  __shared__ _Float16 Qh[64][72], Ql[64][72], Kh[64][72], Kl[64][72];
  const int r = tid >> 2, c = (tid & 3) * 16;
  {
    const size_t qoff = ((size_t)bh * SS + i0 + r) * HD + c;
    const size_t koff = ((size_t)bh * SS + j0 + r) * HD + c;
    *(f16x8*)&Qh[r][c] = *(const f16x8*)(qh + qoff);
    *(f16x8*)&Qh[r][c + 8] = *(const f16x8*)(qh + qoff + 8);
    *(f16x8*)&Ql[r][c] = *(const f16x8*)(ql + qoff);
    *(f16x8*)&Ql[r][c + 8] = *(const f16x8*)(ql + qoff + 8);
    *(f16x8*)&Kh[r][c] = *(const f16x8*)(kh + koff);
    *(f16x8*)&Kh[r][c + 8] = *(const f16x8*)(kh + koff + 8);
    *(f16x8*)&Kl[r][c] = *(const f16x8*)(kl + koff);
    *(f16x8*)&Kl[r][c + 8] = *(const f16x8*)(kl + koff + 8);
  }
  __syncthreads();

  f16x8 a_hi[2], a_lo[2];
#pragma unroll
  for (int ks = 0; ks < 2; ++ks) {
    a_hi[ks] = *(const f16x8*)&Qh[wave * 16 + l16][ks * 32 + quad * 8];
    a_lo[ks] = *(const f16x8*)&Ql[wave * 16 + l16][ks * 32 + quad * 8];
  }
  f32x4 acc[4] = {};
#pragma unroll
  for (int ks = 0; ks < 2; ++ks) {
#pragma unroll
    for (int t = 0; t < 4; ++t) {
      f16x8 b_hi = *(const f16x8*)&Kh[t * 16 + l16][ks * 32 + quad * 8];
      f16x8 b_lo = *(const f16x8*)&Kl[t * 16 + l16][ks * 32 + quad * 8];
      acc[t] = __builtin_amdgcn_mfma_f32_16x16x32_f16(a_hi[ks], b_hi,
                                                      acc[t], 0, 0, 0);
      acc[t] = __builtin_amdgcn_mfma_f32_16x16x32_f16(a_hi[ks], b_lo,
                                                      acc[t], 0, 0, 0);
      acc[t] = __builtin_amdgcn_mfma_f32_16x16x32_f16(a_lo[ks], b_hi,
                                                      acc[t], 0, 0, 0);
    }
  }
  float* sb = s + (size_t)bh * SS * SS;
#pragma unroll
  for (int t = 0; t < 4; ++t) {
#pragma unroll
    for (int r2 = 0; r2 < 4; ++r2) {
      float val = clampf(acc[t][r2], -15.0f, 15.0f);  // inputs finite
      sb[(size_t)(i0 + wave * 16 + quad * 4 + r2) * SS + j0 + t * 16 + l16] = val;
    }
  }
}

// ---------------------------------------------------------------------------
// K_rowstat: per-row fused ma + autopoietic transform (one wave per row,
// 2048 blocks x 64 -- per-row rowred stores, NO atomics).
__global__ __launch_bounds__(64) void k_rowstat(
    const float* __restrict__ s, const float* __restrict__ T,
    float* __restrict__ ma, float* __restrict__ t_un,
    float* __restrict__ rowred) {
  const int row = blockIdx.x;  // b*S + i
  const int b_ = row >> 9, i = row & 511;
  const int lane = threadIdx.x;

  float4 a0 = {0.f, 0.f, 0.f, 0.f}, a1 = {0.f, 0.f, 0.f, 0.f};
#pragma unroll
  for (int hh = 0; hh < NH; ++hh) {
    const float4* p = reinterpret_cast<const float4*>(
                          s + (((size_t)(b_ * NH + hh) * SS) + i) * SS) +
                      lane * 2;
    float4 u0 = p[0], u1 = p[1];
    a0.x += u0.x; a0.y += u0.y; a0.z += u0.z; a0.w += u0.w;
    a1.x += u1.x; a1.y += u1.y; a1.z += u1.z; a1.w += u1.w;
  }
  float m[8] = {a0.x * 0.125f, a0.y * 0.125f, a0.z * 0.125f, a0.w * 0.125f,
                a1.x * 0.125f, a1.y * 0.125f, a1.z * 0.125f, a1.w * 0.125f};
  {
    float4* mp = reinterpret_cast<float4*>(ma + ((size_t)b_ * SS + i) * SS) +
                 lane * 2;
    float4 w0 = {m[0], m[1], m[2], m[3]}, w1v = {m[4], m[5], m[6], m[7]};
    mp[0] = w0;
    mp[1] = w1v;
  }
  float sma = 0.f, sma2 = 0.f, mabs = 0.f;
#pragma unroll
  for (int e = 0; e < 8; ++e) {
    sma += m[e];
    sma2 += m[e] * m[e];
    mabs = fmaxf(mabs, fabsf(m[e]));
  }
  sma = waveRedSum(sma);
  sma2 = waveRedSum(sma2);
  mabs = waveRedMax(mabs);

  float ex[8], esum = 0.f;
#pragma unroll
  for (int e = 0; e < 8; ++e) {
    ex[e] = expf(clampf(m[e], -10.f, 10.f));
    esum += ex[e];
  }
  esum = waveRedSum(esum);
  float inv = 1.0f / esum;
  float Hv[8], sH = 0.f;
#pragma unroll
  for (int e = 0; e < 8; ++e) {
    float p = ex[e] * inv;
    Hv[e] = -p * logf(p + 1e-6f);
    sH += Hv[e];
  }
  sH = waveRedSum(sH);

  float fx[8], fsum = 0.f;
#pragma unroll
  for (int e = 0; e < 8; ++e) {
    fx[e] = expf(3.0f * Hv[e]);
    fsum += fx[e];
  }
  fsum = waveRedSum(fsum);
  float finv = 1.0f / fsum;

  float t[8], st = 0.f, st2 = 0.f;
#pragma unroll
  for (int e = 0; e < 8; ++e) {
    float sa = clampf(m[e], -8.f, 8.f) * 0.05f;
    float pos = (sa + 0.4f) * ((float)NTAB / 0.8f);
    int idx = (int)pos;
    idx = idx < 0 ? 0 : (idx > NTAB - 1 ? NTAB - 1 : idx);
    float frac = pos - (float)idx;
    float g0 = T[idx], g1 = T[idx + 1];
    float sig = g0 + (g1 - g0) * frac;
    t[e] = sig * fx[e] * finv;
    st += t[e];
    st2 += t[e] * t[e];
  }
  st = waveRedSum(st);
  st2 = waveRedSum(st2);
  {
    float4* tp = reinterpret_cast<float4*>(t_un + ((size_t)b_ * SS + i) * SS) +
                 lane * 2;
    float4 w0 = {t[0], t[1], t[2], t[3]}, w1v = {t[4], t[5], t[6], t[7]};
    tp[0] = w0;
    tp[1] = w1v;
  }
  if (lane == 0) {
    float* rp = rowred + (size_t)row * 8;
    rp[0] = sma; rp[1] = sma2; rp[2] = mabs;
    rp[3] = st;  rp[4] = st2;  rp[5] = sH;
  }
}

// ---------------------------------------------------------------------------
// K_av_fused: out = softmax(blend(s)) @ v with NO materialized p. Each block
// first redundantly reduces rowred -> c0/c1/c2 (k_consts folded in; 16 KB
// L2-hot read + 7 block reductions, no atomics). m-tile = 32 rows ->
// grid (16 mb, 32 bh). Stage threads (tid<128) compute unnormalized
// e' = exp(blend)*2^-16, split into LDS, accumulate Z partials.
__global__ __launch_bounds__(256) void k_av_fused(
    const float* __restrict__ s, const float* __restrict__ ma,
    const float* __restrict__ t_un, const float* __restrict__ rowred,
    const float* __restrict__ tau, const _Float16* __restrict__ vth,
    const _Float16* __restrict__ vtl, _Float16* __restrict__ oh,
    _Float16* __restrict__ ol) {
  const int bh = blockIdx.y;
  const int b_ = bh >> 3, hh = bh & 7;
  const int m0 = blockIdx.x * 32;
  const int tid = threadIdx.x;
  const int wave = tid >> 6, lane = tid & 63;
  const int quad = lane >> 4, l16 = lane & 15;

  __shared__ float red[4];
  // ---- per-batch blend constants (formerly k_consts), same reduction order
  float c0, c1, c2;
  {
    const float* r0 = rowred + ((size_t)b_ * SS + tid * 2) * 8;
    const float* r1 = r0 + 8;
    float sma = blockRedSum(r0[0] + r1[0], red);
    float sma2 = blockRedSum(r0[1] + r1[1], red);
    float mabs = blockRedMax(fmaxf(r0[2], r1[2]), red);
    float st = blockRedSum(r0[3] + r1[3], red);
    float st2 = blockRedSum(r0[4] + r1[4], red);
    float sH = blockRedSum(r0[5] + r1[5], red);
    const float N = (float)(SS * SS);
    float eo = sqrtf(sma2) + 1e-4f;
    float et = sqrtf(st2) + 1e-4f;
    float r = clampf(eo / et, 0.8f, 1.2f);
    float tmean = r * st / N;
    float om = sma / N;
    float vart = r * r * fmaxf(st2 / N - (st / N) * (st / N), 0.f);
    float tstd = sqrtf(fmaxf(vart, 0.01f));
    float varo = fmaxf(sma2 / N - om * om, 0.f);
    float ostd = sqrtf(fmaxf(varo, 0.01f));
    float gd = clampf(ostd / tstd, 0.8f, 1.2f);
    float ar = clampf(mabs, 1.f, 10.f);
    float sm = clampf(0.3f / log1pf(ar), 0.1f, 0.5f);
    float ent = sH / N;
    float ne = ent / logf((float)SS);
    float rr = 0.4f * (1.f - clampf(ne, 0.f, 0.4f));
    float G = sm * gd;
    c0 = rr * (1.f - G) * tmean;
    c1 = rr * G * r;
    c2 = rr;
  }
  const float itau = 1.0f / tau[0];

  __shared__ _Float16 Ph[32][40], Pl[32][40];
  __shared__ float Zp[32][4];

  const bool stager = (tid < 128);
  const int srow = tid >> 2;          // 0..31 valid when stager
  const int ci = tid & 3;
  const int schunk = ci * 8;
  const size_t sbase = ((size_t)bh * SS + m0 + (srow & 31)) * SS + schunk;
  const size_t mbase = ((size_t)b_ * SS + m0 + (srow & 31)) * SS + schunk;

  float4 sv0, sv1, mv0, mv1, tv0, tv1;
  if (stager) {
    sv0 = *(const float4*)(s + sbase);
    sv1 = *(const float4*)(s + sbase + 4);
    mv0 = *(const float4*)(ma + mbase);
    mv1 = *(const float4*)(ma + mbase + 4);
    tv0 = *(const float4*)(t_un + mbase);
    tv1 = *(const float4*)(t_un + mbase + 4);
  }

  float zpart = 0.f;
  f32x4 acc[2] = {};
  for (int k0 = 0; k0 < SS; k0 += 32) {
    if (k0) __syncthreads();  // prior-stage LDS reads done
    if (stager) {
      float svv[8] = {sv0.x, sv0.y, sv0.z, sv0.w, sv1.x, sv1.y, sv1.z, sv1.w};
      float mvv[8] = {mv0.x, mv0.y, mv0.z, mv0.w, mv1.x, mv1.y, mv1.z, mv1.w};
      float tvv[8] = {tv0.x, tv0.y, tv0.z, tv0.w, tv1.x, tv1.y, tv1.z, tv1.w};
      f16x8 hv, lv;
#pragma unroll
      for (int j = 0; j < 8; ++j) {
        float vv = (svv[j] + c0 + c1 * tvv[j] - c2 * mvv[j]) * itau;
        float e = expf(vv) * 1.52587890625e-05f;  // * 2^-16
        zpart += e;
        HL r = split16(e);
        hv[j] = r.h;
        lv[j] = r.l;
      }
      *(f16x8*)&Ph[srow][schunk] = hv;
      *(f16x8*)&Pl[srow][schunk] = lv;
    }
    __syncthreads();
    if (stager && k0 + 32 < SS) {
      sv0 = *(const float4*)(s + sbase + k0 + 32);
      sv1 = *(const float4*)(s + sbase + k0 + 36);
      mv0 = *(const float4*)(ma + mbase + k0 + 32);
      mv1 = *(const float4*)(ma + mbase + k0 + 36);
      tv0 = *(const float4*)(t_un + mbase + k0 + 32);
      tv1 = *(const float4*)(t_un + mbase + k0 + 36);
    }
    const size_t boff = ((size_t)bh * HD + wave * 16 + l16) * SS + k0 + quad * 8;
    f16x8 bh_ = *(const f16x8*)(vth + boff);
    f16x8 bl_ = *(const f16x8*)(vtl + boff);
#pragma unroll
    for (int mt = 0; mt < 2; ++mt) {
      f16x8 ah = *(const f16x8*)&Ph[mt * 16 + l16][quad * 8];
      f16x8 al = *(const f16x8*)&Pl[mt * 16 + l16][quad * 8];
      acc[mt] = __builtin_amdgcn_mfma_f32_16x16x32_f16(ah, bh_, acc[mt], 0, 0, 0);
      acc[mt] = __builtin_amdgcn_mfma_f32_16x16x32_f16(ah, bl_, acc[mt], 0, 0, 0);
      acc[mt] = __builtin_amdgcn_mfma_f32_16x16x32_f16(al, bh_, acc[mt], 0, 0, 0);
    }
  }
  __syncthreads();
  if (stager) Zp[srow][ci] = zpart;
  __syncthreads();
#pragma unroll
  for (int mt = 0; mt < 2; ++mt) {
#pragma unroll
    for (int r = 0; r < 4; ++r) {
      const int lr = mt * 16 + quad * 4 + r;  // local row 0..31
      const float Z = Zp[lr][0] + Zp[lr][1] + Zp[lr][2] + Zp[lr][3];
      const float oV = acc[mt][r] / Z;
      const int si = m0 + lr;
      const size_t idx =
          ((size_t)(b_ * SS + si)) * EE + hh * HD + wave * 16 + l16;
      HL sp = split16(oV);
      oh[idx] = sp.h;
      ol[idx] = sp.l;
    }
  }
}

// ---------------------------------------------------------------------------
// K_out: LDS-staged 3-term f16 MFMA GEMM with register-prefetch pipelining,
// fp32 output + bias. grid (8 nb, 32 mb), block 256.
__global__ __launch_bounds__(256) void k_out_mfma(
    const _Float16* __restrict__ oh, const _Float16* __restrict__ ol,
    const _Float16* __restrict__ Wth, const _Float16* __restrict__ Wtl,
    const float* __restrict__ bo, float* __restrict__ out) {
  const int tid = threadIdx.x;
  const int wave = tid >> 6, lane = tid & 63;
  const int quad = lane >> 4, l16 = lane & 15;
  const int m0 = blockIdx.y * 64;
  const int n0 = blockIdx.x * 64;
  const _Float16* Bh = Wth + (size_t)3 * EE * EE;  // Wo^T
  const _Float16* Bl = Wtl + (size_t)3 * EE * EE;

  __shared__ _Float16 LAh[64][72], LAl[64][72], LBh[64][72], LBl[64][72];

  const int sr0 = tid >> 3, sc0 = (tid & 7) * 8;
  const int sr1 = sr0 + 32;

  f16x8 rA0h = *(const f16x8*)(oh + (size_t)(m0 + sr0) * EE + sc0);
  f16x8 rA0l = *(const f16x8*)(ol + (size_t)(m0 + sr0) * EE + sc0);
  f16x8 rB0h = *(const f16x8*)(Bh + (size_t)(n0 + sr0) * EE + sc0);
  f16x8 rB0l = *(const f16x8*)(Bl + (size_t)(n0 + sr0) * EE + sc0);
  f16x8 rA1h = *(const f16x8*)(oh + (size_t)(m0 + sr1) * EE + sc0);
  f16x8 rA1l = *(const f16x8*)(ol + (size_t)(m0 + sr1) * EE + sc0);
  f16x8 rB1h = *(const f16x8*)(Bh + (size_t)(n0 + sr1) * EE + sc0);
  f16x8 rB1l = *(const f16x8*)(Bl + (size_t)(n0 + sr1) * EE + sc0);

  f32x4 acc[4] = {};
  for (int k0 = 0; k0 < EE; k0 += 64) {
    if (k0) __syncthreads();
    *(f16x8*)&LAh[sr0][sc0] = rA0h;
    *(f16x8*)&LAl[sr0][sc0] = rA0l;
    *(f16x8*)&LBh[sr0][sc0] = rB0h;
    *(f16x8*)&LBl[sr0][sc0] = rB0l;
    *(f16x8*)&LAh[sr1][sc0] = rA1h;
    *(f16x8*)&LAl[sr1][sc0] = rA1l;
    *(f16x8*)&LBh[sr1][sc0] = rB1h;
    *(f16x8*)&LBl[sr1][sc0] = rB1l;
    __syncthreads();
    if (k0 + 64 < EE) {
      const int kn = k0 + 64;
      rA0h = *(const f16x8*)(oh + (size_t)(m0 + sr0) * EE + kn + sc0);
      rA0l = *(const f16x8*)(ol + (size_t)(m0 + sr0) * EE + kn + sc0);
      rB0h = *(const f16x8*)(Bh + (size_t)(n0 + sr0) * EE + kn + sc0);
      rB0l = *(const f16x8*)(Bl + (size_t)(n0 + sr0) * EE + kn + sc0);
      rA1h = *(const f16x8*)(oh + (size_t)(m0 + sr1) * EE + kn + sc0);
      rA1l = *(const f16x8*)(ol + (size_t)(m0 + sr1) * EE + kn + sc0);
      rB1h = *(const f16x8*)(Bh + (size_t)(n0 + sr1) * EE + kn + sc0);
      rB1l = *(const f16x8*)(Bl + (size_t)(n0 + sr1) * EE + kn + sc0);
    }
#pragma unroll
    for (int kk = 0; kk < 64; kk += 32) {
      f16x8 ah = *(const f16x8*)&LAh[wave * 16 + l16][kk + quad * 8];
      f16x8 al = *(const f16x8*)&LAl[wave * 16 + l16][kk + quad * 8];
#pragma unroll
      for (int nt = 0; nt < 4; ++nt) {
        f16x8 bhf = *(const f16x8*)&LBh[nt * 16 + l16][kk + quad * 8];
        f16x8 blf = *(const f16x8*)&LBl[nt * 16 + l16][kk + quad * 8];
        acc[nt] = __builtin_amdgcn_mfma_f32_16x16x32_f16(ah, bhf, acc[nt], 0, 0, 0);
        acc[nt] = __builtin_amdgcn_mfma_f32_16x16x32_f16(ah, blf, acc[nt], 0, 0, 0);
        acc[nt] = __builtin_amdgcn_mfma_f32_16x16x32_f16(al, bhf, acc[nt], 0, 0, 0);
      }
    }
  }
  const int mbase = m0 + wave * 16 + quad * 4;
#pragma unroll
  for (int nt = 0; nt < 4; ++nt) {
    const int col = n0 + nt * 16 + l16;
    const float bb = bo[col];
#pragma unroll
    for (int r = 0; r < 4; ++r) {
      const int m = mbase + r;
      out[(size_t)m * EE + col] = acc[nt][r] + bb;
    }
  }
}

// ---------------------------------------------------------------------------
extern "C" void kernel_launch(void* const* d_in, const int* in_sizes, int n_in,
                              void* d_out, int out_size, void* d_ws,
                              size_t ws_size, hipStream_t stream) {
  const float* x = (const float*)d_in[0];
  const float* Wq = (const float*)d_in[1];
  const float* bq = (const float*)d_in[2];
  const float* Wk = (const float*)d_in[3];
  const float* bk = (const float*)d_in[4];
  const float* Wv = (const float*)d_in[5];
  const float* bv = (const float*)d_in[6];
  const float* Wo = (const float*)d_in[7];
  const float* bo = (const float*)d_in[8];
  const float* w1 = (const float*)d_in[9];
  const float* b1 = (const float*)d_in[10];
  const float* w2 = (const float*)d_in[11];
  const float* b2 = (const float*)d_in[12];
  const float* tau = (const float*)d_in[13];
  float* out = (float*)d_out;

  const size_t NX = (size_t)2048 * EE;           // 1M elems (o)
  const size_t NW = (size_t)4 * EE * EE;         // 1M elems (4 W's)
  const size_t NQK = (size_t)BB * NH * SS * HD;  // 1M elems
  const size_t NS = (size_t)BB * NH * SS * SS;   // 8.39M elems

  _Float16* Wth = (_Float16*)d_ws;
  _Float16* Wtl = Wth + NW;
  _Float16* qh = Wtl + NW;
  _Float16* ql = qh + NQK;
  _Float16* kh = ql + NQK;
  _Float16* kl = kh + NQK;
  _Float16* vth = kl + NQK;
  _Float16* vtl = vth + NQK;
  _Float16* oh = vtl + NQK;
  _Float16* ol = oh + NX;
  float* s = (float*)(ol + NX);
  float* ma = s + NS;
  float* t_un = ma + (size_t)BB * SS * SS;
  float* T = t_un + (size_t)BB * SS * SS;
  float* rowred = T + 8192;            // 2048*8

  k_prep<<<256, 256, 0, stream>>>(Wq, Wk, Wv, Wo, Wth, Wtl);
  k_qkv_mfma<<<dim3(8, 32, 3), 256, 0, stream>>>(x, Wth, Wtl, bq, bk, bv, w1,
                                                 b1, w2, b2, T, qh, ql, kh, kl,
                                                 vth, vtl);
  k_scores_mfma<<<dim3(8, 8, 32), 256, 0, stream>>>(qh, ql, kh, kl, s);
  k_rowstat<<<2048, 64, 0, stream>>>(s, T, ma, t_un, rowred);
  k_av_fused<<<dim3(16, 32), 256, 0, stream>>>(s, ma, t_un, rowred, tau, vth,
                                               vtl, oh, ol);
  k_out_mfma<<<dim3(8, 32), 256, 0, stream>>>(oh, ol, Wth, Wtl, bo, out);
}